// Round 6
// baseline (4757.581 us; speedup 1.0000x reference)
//
#include <hip/hip_runtime.h>
#include <math.h>

#define NPTS 8192
#define KNN 20

// ---------------------------------------------------------------------------
// sq[i] = sum_d x[i][d]^2
// ---------------------------------------------------------------------------
__global__ void sqnorm_kernel(const float* __restrict__ x, int ldx, int D,
                              float* __restrict__ sq) {
  int i = blockIdx.x * blockDim.x + threadIdx.x;
  if (i >= NPTS) return;
  const float* xr = x + (size_t)i * ldx;
  float s = 0.f;
  for (int d = 0; d < D; ++d) { float v = xr[d]; s += v * v; }
  sq[i] = s;
}

// ---------------------------------------------------------------------------
// Branchless sorted-insert (ascending). Caller guards with val < d[19].
// Strict < keeps earlier-scanned (smaller j) entries ahead on ties.
// All indices compile-time (full unroll) -> stays in VGPRs (rule #20).
// ---------------------------------------------------------------------------
__device__ __forceinline__ void insert20(float (&d)[KNN], int (&ix)[KNN],
                                         float val, int j) {
  float cv = val; int ci = j;
#pragma unroll
  for (int r = 0; r < KNN; ++r) {
    bool sw = cv < d[r];
    float od = d[r]; int oi = ix[r];
    d[r] = sw ? cv : od; ix[r] = sw ? ci : oi;
    cv = sw ? od : cv;  ci = sw ? oi : ci;
  }
}

// tie-aware version for the merge (dist, then index)
__device__ __forceinline__ void insert20t(float (&d)[KNN], int (&ix)[KNN],
                                          float val, int j) {
  float cv = val; int ci = j;
#pragma unroll
  for (int r = 0; r < KNN; ++r) {
    bool sw = (cv < d[r]) || (cv == d[r] && ci < ix[r]);
    float od = d[r]; int oi = ix[r];
    d[r] = sw ? cv : od; ix[r] = sw ? ci : oi;
    cv = sw ? od : cv;  ci = sw ? oi : ci;
  }
}

// ---------------------------------------------------------------------------
// 64-D kNN pass: fused fp32 GEMM + top-20 selection.
// Grid: (64 query-blocks, 8 candidate-chunks), 256 threads, 48 KB LDS.
// __launch_bounds__(256,3): 3 waves/EU -> 3 blocks/CU (LDS 3x48=144<=160KB,
// VGPR cap ~170 > current 128). Round-5 profile: VALUBusy 53%, Occ 16% --
// more resident waves hide barrier drains + LDS latency.
// Every private-array access is compile-time-indexed (rule #20).
// Fragment map: thread (am = t&15, bg = (t>>4)&15) owns queries
// {4am..4am+3, 64+4am..+3} x cands {4bg..4bg+3, 64+4bg..+3}.
// Score swizzle g(row)=((row&7)^((row>>2)&7))<<2: conflict-free write+read.
// ---------------------------------------------------------------------------
#define WRITE_S(QR, BASE)                                                   \
  {                                                                         \
    const int cc = (4 * bg) & 31;                                           \
    const int jbase = cb + (QR)*32 + cc;                                    \
    _Pragma("unroll") for (int u = 0; u < 8; ++u) {                         \
      const int row = 4 * am + (u & 3) + 64 * (u >> 2);                     \
      const int gq = qb * 128 + row;                                        \
      const int sw = ((row & 7) ^ ((row >> 2) & 7)) << 2;                   \
      float w0 = fmaf(-2.f, acc[u][(BASE) + 0], sc[(BASE) + 0]);            \
      float w1 = fmaf(-2.f, acc[u][(BASE) + 1], sc[(BASE) + 1]);            \
      float w2 = fmaf(-2.f, acc[u][(BASE) + 2], sc[(BASE) + 2]);            \
      float w3 = fmaf(-2.f, acc[u][(BASE) + 3], sc[(BASE) + 3]);            \
      if (jbase + 0 == gq) w0 = INFINITY;                                   \
      if (jbase + 1 == gq) w1 = INFINITY;                                   \
      if (jbase + 2 == gq) w2 = INFINITY;                                   \
      if (jbase + 3 == gq) w3 = INFINITY;                                   \
      *(float4*)&S[row * 32 + (cc ^ sw)] = make_float4(w0, w1, w2, w3);     \
    }                                                                       \
  }

template <int LDX>
__global__ __launch_bounds__(256, 3) void knn_gemm_kernel(
    const float* __restrict__ x, const float* __restrict__ sq,
    float* __restrict__ pd, int* __restrict__ pj) {
  __shared__ float Qs[64 * 128];   // [k][q]
  __shared__ float CsS[32 * 128];  // Cs: [k2][n] during compute; S: [q][cc]
  float* const Cs = CsS;
  float* const S = CsS;
  const int t = threadIdx.x;
  const int qb = blockIdx.x;  // 0..63
  const int ch = blockIdx.y;  // 0..7
  const int am = t & 15;
  const int bg = (t >> 4) & 15;

  // stage Q tile once: thread handles q = t&127, k-half (t>>7)*32
  {
    const int q = t & 127;
    const int k0 = (t >> 7) * 32;
    const float* src = &x[(size_t)(qb * 128 + q) * LDX + k0];
#pragma unroll
    for (int c = 0; c < 8; ++c) {
      float4 v = *(const float4*)&src[c * 4];
      Qs[(k0 + c * 4 + 0) * 128 + q] = v.x;
      Qs[(k0 + c * 4 + 1) * 128 + q] = v.y;
      Qs[(k0 + c * 4 + 2) * 128 + q] = v.z;
      Qs[(k0 + c * 4 + 3) * 128 + q] = v.w;
    }
  }

  const int selq = t & 127, part = t >> 7;
  float dreg[KNN]; int ireg[KNN];
#pragma unroll
  for (int r = 0; r < KNN; ++r) { dreg[r] = INFINITY; ireg[r] = 0x7fffffff; }

  for (int tile = 0; tile < 8; ++tile) {
    const int cb = ch * 1024 + tile * 128;
    float acc[8][8] = {};
    for (int kh = 0; kh < 2; ++kh) {
      __syncthreads();  // prev S-reads / prev compute done -> CsS reusable
      {
        const int n = t & 127;
        const int k0 = (t >> 7) * 16;
        const float* src = &x[(size_t)(cb + n) * LDX + kh * 32 + k0];
#pragma unroll
        for (int c = 0; c < 4; ++c) {
          float4 v = *(const float4*)&src[c * 4];
          Cs[(k0 + c * 4 + 0) * 128 + n] = v.x;
          Cs[(k0 + c * 4 + 1) * 128 + n] = v.y;
          Cs[(k0 + c * 4 + 2) * 128 + n] = v.z;
          Cs[(k0 + c * 4 + 3) * 128 + n] = v.w;
        }
      }
      __syncthreads();
#pragma unroll 4
      for (int k2 = 0; k2 < 32; ++k2) {
        const int k = kh * 32 + k2;
        float4 A0 = *(const float4*)&Qs[k * 128 + 4 * am];
        float4 A1 = *(const float4*)&Qs[k * 128 + 4 * am + 64];
        float4 B0 = *(const float4*)&Cs[k2 * 128 + 4 * bg];
        float4 B1 = *(const float4*)&Cs[k2 * 128 + 4 * bg + 64];
        float a[8] = {A0.x, A0.y, A0.z, A0.w, A1.x, A1.y, A1.z, A1.w};
        float b[8] = {B0.x, B0.y, B0.z, B0.w, B1.x, B1.y, B1.z, B1.w};
#pragma unroll
        for (int u = 0; u < 8; ++u)
#pragma unroll
          for (int v = 0; v < 8; ++v) acc[u][v] = fmaf(a[u], b[v], acc[u][v]);
      }
    }
    // sq for my 8 candidates (compile-time indexed everywhere below)
    float4 s0 = *(const float4*)&sq[cb + 4 * bg];
    float4 s1 = *(const float4*)&sq[cb + 4 * bg + 64];
    float sc[8] = {s0.x, s0.y, s0.z, s0.w, s1.x, s1.y, s1.z, s1.w};

    const int qlow = bg >> 3;  // quarter holding my low 4 candidates
    for (int qr = 0; qr < 4; ++qr) {
      __syncthreads();  // S free (prev phase read / compute done)
      if (qr == qlow) WRITE_S(qr, 0);          // acc[u][0..3], literal base
      if (qr == 2 + qlow) WRITE_S(qr, 4);      // acc[u][4..7], literal base
      __syncthreads();
      const int swr = ((selq & 7) ^ ((selq >> 2) & 7)) << 2;
      const int jb = cb + qr * 32;
#pragma unroll
      for (int g_ = 0; g_ < 4; ++g_) {
        const int cc = part * 16 + g_ * 4;
        float4 sv = *(const float4*)&S[selq * 32 + (cc ^ swr)];
        float vv[4] = {sv.x, sv.y, sv.z, sv.w};
#pragma unroll
        for (int e = 0; e < 4; ++e) {
          if (vv[e] < dreg[KNN - 1]) insert20(dreg, ireg, vv[e], jb + cc + e);
        }
      }
    }
  }
  // write partial list (16 lists: ch*2 + part)
  const int l = ch * 2 + part;
  float* pdq = pd + ((size_t)l * NPTS + (qb * 128 + selq)) * KNN;
  int* pjq = pj + ((size_t)l * NPTS + (qb * 128 + selq)) * KNN;
#pragma unroll
  for (int r = 0; r < KNN; ++r) { pdq[r] = dreg[r]; pjq[r] = ireg[r]; }
}

// ---------------------------------------------------------------------------
// 3-D kNN pass: thread-per-query streaming over LDS candidate tiles.
// Grid: (32 query-blocks, 16 chunks), 256 threads -> 512 visits/thread
// (halved from round 5; selection is the cost). 16 partial lists.
// ---------------------------------------------------------------------------
__global__ __launch_bounds__(256) void knn_d3_kernel(
    const float* __restrict__ x, const float* __restrict__ sq,
    float* __restrict__ pd, int* __restrict__ pj) {
  __shared__ float4 Ct[256];  // {x, y, z, sq}
  const int t = threadIdx.x;
  const int q = blockIdx.x * 256 + t;
  const int ch = blockIdx.y;
  const float xi0 = x[q * 3], xi1 = x[q * 3 + 1], xi2 = x[q * 3 + 2];
  float dreg[KNN]; int ireg[KNN];
#pragma unroll
  for (int r = 0; r < KNN; ++r) { dreg[r] = INFINITY; ireg[r] = 0x7fffffff; }

  for (int tile = 0; tile < 2; ++tile) {
    const int cb = ch * 512 + tile * 256;
    __syncthreads();
    Ct[t] = make_float4(x[(cb + t) * 3], x[(cb + t) * 3 + 1],
                        x[(cb + t) * 3 + 2], sq[cb + t]);
    __syncthreads();
#pragma unroll 1
    for (int c = 0; c < 256; ++c) {
      float4 cv = Ct[c];
      int j = cb + c;
      float val = fmaf(-2.f, xi0 * cv.x + xi1 * cv.y + xi2 * cv.z, cv.w);
      if (j != q && val < dreg[KNN - 1]) insert20(dreg, ireg, val, j);
    }
  }
  float* pdq = pd + ((size_t)ch * NPTS + q) * KNN;
  int* pjq = pj + ((size_t)ch * NPTS + q) * KNN;
#pragma unroll
  for (int r = 0; r < KNN; ++r) { pdq[r] = dreg[r]; pjq[r] = ireg[r]; }
}

// ---------------------------------------------------------------------------
// merge L partial top-20 lists per query -> final 20 indices
// ---------------------------------------------------------------------------
__global__ __launch_bounds__(128) void knn_merge_kernel(
    const float* __restrict__ pd, const int* __restrict__ pj,
    int* __restrict__ idx_out, int L) {
  const int q = blockIdx.x * 128 + threadIdx.x;
  float d[KNN]; int ix[KNN];
#pragma unroll
  for (int r = 0; r < KNN; ++r) { d[r] = INFINITY; ix[r] = 0x7fffffff; }
#pragma unroll 1
  for (int l = 0; l < L; ++l) {
    const float* pdq = pd + ((size_t)l * NPTS + q) * KNN;
    const int* pjq = pj + ((size_t)l * NPTS + q) * KNN;
#pragma unroll 1
    for (int r = 0; r < KNN; ++r) {
      float val = pdq[r]; int j = pjq[r];
      bool worse = (val > d[KNN - 1]) ||
                   (val == d[KNN - 1] && j > ix[KNN - 1]);
      if (!worse) insert20t(d, ix, val, j);
    }
  }
#pragma unroll
  for (int r = 0; r < KNN; ++r) idx_out[(size_t)q * KNN + r] = ix[r];
}

// ---------------------------------------------------------------------------
// edge conv: out[i][c] = max_k relu(b + [x_i, x_j-x_i] . W1[:,c])
// 4 points per 256-thread block (1-wave blocks cap waves/CU at block-slots).
// ---------------------------------------------------------------------------
__global__ __launch_bounds__(256) void edgeconv_kernel(
    const float* __restrict__ x, const int* __restrict__ idx,
    const float* __restrict__ W1, const float* __restrict__ b1,
    float* __restrict__ out) {
  const int i = blockIdx.x * 4 + (threadIdx.x >> 6);
  const int c = threadIdx.x & 63;
  float w0 = W1[c], w1 = W1[64 + c], w2 = W1[128 + c];
  float w3 = W1[192 + c], w4 = W1[256 + c], w5 = W1[320 + c];
  float xi0 = x[3 * i], xi1 = x[3 * i + 1], xi2 = x[3 * i + 2];
  float base = b1[c] + xi0 * w0 + xi1 * w1 + xi2 * w2;
  float m = -INFINITY;
#pragma unroll
  for (int k = 0; k < KNN; ++k) {
    int j = idx[i * KNN + k];
    float d0 = x[3 * j] - xi0, d1 = x[3 * j + 1] - xi1, d2 = x[3 * j + 2] - xi2;
    float h = base + d0 * w3 + d1 * w4 + d2 * w5;
    m = fmaxf(m, fmaxf(h, 0.f));
  }
  out[(size_t)i * 64 + c] = m;
}

// ---------------------------------------------------------------------------
// dilate: dil[c] = max_k xin[idx[k]][c]; out = relu(dil.W + b) - xin
// 4 points per 256-thread block.
// ---------------------------------------------------------------------------
__global__ __launch_bounds__(256) void dilate_kernel(
    const float* __restrict__ xin, int ldin, const int* __restrict__ idx,
    const float* __restrict__ W, const float* __restrict__ bias,
    float* __restrict__ out, int ldout) {
  const int g = threadIdx.x >> 6;
  const int i = blockIdx.x * 4 + g;
  const int c = threadIdx.x & 63;
  __shared__ float dil[4][64];
  float m = -INFINITY;
#pragma unroll
  for (int k = 0; k < KNN; ++k) {
    int j = idx[i * KNN + k];
    m = fmaxf(m, xin[(size_t)j * ldin + c]);
  }
  dil[g][c] = m;
  __syncthreads();
  float acc = bias[c];
#pragma unroll
  for (int d = 0; d < 64; ++d) acc = fmaf(dil[g][d], W[d * 64 + c], acc);
  out[(size_t)i * ldout + c] = fmaxf(acc, 0.f) - xin[(size_t)i * ldin + c];
}

// ---------------------------------------------------------------------------
// BM=128 x BN tile fp32 GEMM, 256 threads, 8x(BN/16)/thread, relu epilogue.
// BN = 128 or 64. Requires M%128==0, N%BN==0, K%16==0.
// ---------------------------------------------------------------------------
template <int BN>
__global__ __launch_bounds__(256) void gemm128_kernel(
    const float* __restrict__ A, int K, int ldA, const float* __restrict__ W,
    int N, const float* __restrict__ bias, float* __restrict__ C, int ldC,
    int relu) {
  constexpr int VN = BN / 16;  // cands per thread (8 or 4)
  __shared__ float As[16 * 128];  // [k][m]
  __shared__ float Bs[16 * BN];   // [k][n]
  const int t = threadIdx.x;
  const int bn = blockIdx.x * BN;
  const int bm = blockIdx.y * 128;
  const int am = t & 15;
  const int bg = (t >> 4) & 15;
  float acc[8][VN] = {};

  for (int k0 = 0; k0 < K; k0 += 16) {
    __syncthreads();
    {  // A: thread loads 8 k-floats of row m = t&127
      const int m = t & 127;
      const int ka = (t >> 7) * 8;
      const float* src = &A[(size_t)(bm + m) * ldA + k0 + ka];
      float4 v0 = *(const float4*)&src[0];
      float4 v1 = *(const float4*)&src[4];
      As[(ka + 0) * 128 + m] = v0.x;
      As[(ka + 1) * 128 + m] = v0.y;
      As[(ka + 2) * 128 + m] = v0.z;
      As[(ka + 3) * 128 + m] = v0.w;
      As[(ka + 4) * 128 + m] = v1.x;
      As[(ka + 5) * 128 + m] = v1.y;
      As[(ka + 6) * 128 + m] = v1.z;
      As[(ka + 7) * 128 + m] = v1.w;
    }
    if constexpr (BN == 128) {  // B: 16k x 128n, 8 floats/thread
      const int kb = t >> 4;
      const int n8 = (t & 15) * 8;
      const float* src = &W[(size_t)(k0 + kb) * N + bn + n8];
      float4 v0 = *(const float4*)&src[0];
      float4 v1 = *(const float4*)&src[4];
      *(float4*)&Bs[kb * BN + n8] = v0;
      *(float4*)&Bs[kb * BN + n8 + 4] = v1;
    } else {  // BN == 64: 16k x 64n, 4 floats/thread
      const int kb = t >> 4;
      const int n4 = (t & 15) * 4;
      const float* src = &W[(size_t)(k0 + kb) * N + bn + n4];
      *(float4*)&Bs[kb * BN + n4] = *(const float4*)&src[0];
    }
    __syncthreads();
#pragma unroll
    for (int k = 0; k < 16; ++k) {
      float4 A0 = *(const float4*)&As[k * 128 + 4 * am];
      float4 A1 = *(const float4*)&As[k * 128 + 4 * am + 64];
      float a[8] = {A0.x, A0.y, A0.z, A0.w, A1.x, A1.y, A1.z, A1.w};
      float b[VN];
      float4 B0 = *(const float4*)&Bs[k * BN + 4 * bg];
      b[0] = B0.x; b[1] = B0.y; b[2] = B0.z; b[3] = B0.w;
      if constexpr (BN == 128) {
        float4 B1 = *(const float4*)&Bs[k * BN + 4 * bg + 64];
        b[4] = B1.x; b[5] = B1.y; b[6] = B1.z; b[7] = B1.w;
      }
#pragma unroll
      for (int u = 0; u < 8; ++u)
#pragma unroll
        for (int v = 0; v < VN; ++v) acc[u][v] = fmaf(a[u], b[v], acc[u][v]);
    }
  }
#pragma unroll
  for (int u = 0; u < 8; ++u) {
    const int m = bm + 4 * am + (u & 3) + 64 * (u >> 2);
#pragma unroll
    for (int vq = 0; vq < VN / 4; ++vq) {
      const int n = bn + 4 * bg + 64 * vq;
      float4 o;
      float* po = (float*)&o;
#pragma unroll
      for (int e = 0; e < 4; ++e) {
        float val = acc[u][vq * 4 + e] + bias[n + e];
        po[e] = relu ? fmaxf(val, 0.f) : val;
      }
      *(float4*)&C[(size_t)m * ldC + n] = o;
    }
  }
}

// ---------------------------------------------------------------------------
// logits = h3 @ Wm3 + bm3 ; out = log_softmax(logits)
// ---------------------------------------------------------------------------
__global__ __launch_bounds__(256) void final_kernel(
    const float* __restrict__ h3, const float* __restrict__ Wm3,
    const float* __restrict__ bm3, float* __restrict__ out) {
  __shared__ float hs[16][132];
  const int tid = threadIdx.x;
  const int r = tid >> 4, c = tid & 15;
  const int row0 = blockIdx.x * 16;
#pragma unroll
  for (int l = tid; l < 2048; l += 256)
    hs[l >> 7][l & 127] = h3[(size_t)row0 * 128 + l];
  __syncthreads();
  float acc = bm3[c];
#pragma unroll
  for (int d = 0; d < 128; ++d) acc = fmaf(hs[r][d], Wm3[d * 16 + c], acc);
  float mx = acc;
#pragma unroll
  for (int o = 8; o >= 1; o >>= 1) mx = fmaxf(mx, __shfl_xor(mx, o, 16));
  float e = expf(acc - mx);
  float s = e;
#pragma unroll
  for (int o = 8; o >= 1; o >>= 1) s += __shfl_xor(s, o, 16);
  out[(size_t)(row0 + r) * 16 + c] = (acc - mx) - logf(s);
}

// ---------------------------------------------------------------------------
extern "C" void kernel_launch(void* const* d_in, const int* in_sizes, int n_in,
                              void* d_out, int out_size, void* d_ws,
                              size_t ws_size, hipStream_t stream) {
  const float* x = (const float*)d_in[0];
  const float* W1 = (const float*)d_in[1];
  const float* b1 = (const float*)d_in[2];
  const float* Wd1 = (const float*)d_in[3];
  const float* bd1 = (const float*)d_in[4];
  const float* Wd2 = (const float*)d_in[5];
  const float* bd2 = (const float*)d_in[6];
  const float* Wd3 = (const float*)d_in[7];
  const float* bd3 = (const float*)d_in[8];
  const float* Wl = (const float*)d_in[9];
  const float* bl = (const float*)d_in[10];
  const float* Wm1 = (const float*)d_in[11];
  const float* bm1 = (const float*)d_in[12];
  const float* Wm2 = (const float*)d_in[13];
  const float* bm2 = (const float*)d_in[14];
  const float* Wm3 = (const float*)d_in[15];
  const float* bm3 = (const float*)d_in[16];
  float* out = (float*)d_out;

  char* ws = (char*)d_ws;
  float* sq = (float*)(ws + 0);              // 32 KB
  int* idxA = (int*)(ws + 32768);            // 640 KB
  float* xfeat = (float*)(ws + 1343488);     // 2 MB   [8192 x 64]
  float* xcat = (float*)(ws + 3440640);      // 6 MB   [8192 x 192]
  float* h1 = (float*)(ws + 9732096);        // 32 MB  [8192 x 1024]
  float* h2 = (float*)(ws + 43286528);       // 8 MB   [8192 x 256]
  float* h3 = (float*)(ws + 51675136);       // 4 MB   [8192 x 128]
  float* x1 = xcat;
  float* x2 = xcat + 64;
  float* x3 = xcat + 128;
  // partial knn lists live in the (not-yet-used) h1 region: 16 lists
  float* pd = h1;                            // 10.5 MB
  int* pj = (int*)(h1 + 16 * NPTS * KNN);    // 10.5 MB

  // stage 1: edge conv on xyz
  sqnorm_kernel<<<32, 256, 0, stream>>>(x, 3, 3, sq);
  knn_d3_kernel<<<dim3(32, 16), 256, 0, stream>>>(x, sq, pd, pj);
  knn_merge_kernel<<<64, 128, 0, stream>>>(pd, pj, idxA, 16);
  edgeconv_kernel<<<NPTS / 4, 256, 0, stream>>>(x, idxA, W1, b1, xfeat);

  // stage 2: three dilate blocks (kNN in 64-D feature space each)
  sqnorm_kernel<<<32, 256, 0, stream>>>(xfeat, 64, 64, sq);
  knn_gemm_kernel<64><<<dim3(64, 8), 256, 0, stream>>>(xfeat, sq, pd, pj);
  knn_merge_kernel<<<64, 128, 0, stream>>>(pd, pj, idxA, 16);
  dilate_kernel<<<NPTS / 4, 256, 0, stream>>>(xfeat, 64, idxA, Wd1, bd1, x1,
                                              192);

  sqnorm_kernel<<<32, 256, 0, stream>>>(x1, 192, 64, sq);
  knn_gemm_kernel<192><<<dim3(64, 8), 256, 0, stream>>>(x1, sq, pd, pj);
  knn_merge_kernel<<<64, 128, 0, stream>>>(pd, pj, idxA, 16);
  dilate_kernel<<<NPTS / 4, 256, 0, stream>>>(x1, 192, idxA, Wd2, bd2, x2,
                                              192);

  sqnorm_kernel<<<32, 256, 0, stream>>>(x2, 192, 64, sq);
  knn_gemm_kernel<192><<<dim3(64, 8), 256, 0, stream>>>(x2, sq, pd, pj);
  knn_merge_kernel<<<64, 128, 0, stream>>>(pd, pj, idxA, 16);
  dilate_kernel<<<NPTS / 4, 256, 0, stream>>>(x2, 192, idxA, Wd3, bd3, x3,
                                              192);

  // stage 3: MLP head
  gemm128_kernel<128><<<dim3(1024 / 128, NPTS / 128), 256, 0, stream>>>(
      xcat, 192, 192, Wl, 1024, bl, h1, 1024, 1);
  gemm128_kernel<64><<<dim3(256 / 64, NPTS / 128), 256, 0, stream>>>(
      h1, 1024, 1024, Wm1, 256, bm1, h2, 256, 1);
  gemm128_kernel<64><<<dim3(128 / 64, NPTS / 128), 256, 0, stream>>>(
      h2, 256, 256, Wm2, 128, bm2, h3, 128, 1);
  final_kernel<<<NPTS / 16, 256, 0, stream>>>(h3, Wm3, bm3, out);
}

// Round 7
// 2950.753 us; speedup vs baseline: 1.6123x; 1.6123x over previous
//
#include <hip/hip_runtime.h>
#include <math.h>

#define NPTS 8192
#define KNN 20

// ---------------------------------------------------------------------------
// sq[i] = sum_d x[i][d]^2
// ---------------------------------------------------------------------------
__global__ void sqnorm_kernel(const float* __restrict__ x, int ldx, int D,
                              float* __restrict__ sq) {
  int i = blockIdx.x * blockDim.x + threadIdx.x;
  if (i >= NPTS) return;
  const float* xr = x + (size_t)i * ldx;
  float s = 0.f;
  for (int d = 0; d < D; ++d) { float v = xr[d]; s += v * v; }
  sq[i] = s;
}

// ---------------------------------------------------------------------------
// Branchless sorted-insert (ascending). Caller guards with val < d[19].
// Strict < keeps earlier-scanned (smaller j) entries ahead on ties.
// All indices compile-time (full unroll) -> stays in VGPRs (rule #20).
// ---------------------------------------------------------------------------
__device__ __forceinline__ void insert20(float (&d)[KNN], int (&ix)[KNN],
                                         float val, int j) {
  float cv = val; int ci = j;
#pragma unroll
  for (int r = 0; r < KNN; ++r) {
    bool sw = cv < d[r];
    float od = d[r]; int oi = ix[r];
    d[r] = sw ? cv : od; ix[r] = sw ? ci : oi;
    cv = sw ? od : cv;  ci = sw ? oi : ci;
  }
}

// tie-aware version for the merge (dist, then index)
__device__ __forceinline__ void insert20t(float (&d)[KNN], int (&ix)[KNN],
                                          float val, int j) {
  float cv = val; int ci = j;
#pragma unroll
  for (int r = 0; r < KNN; ++r) {
    bool sw = (cv < d[r]) || (cv == d[r] && ci < ix[r]);
    float od = d[r]; int oi = ix[r];
    d[r] = sw ? cv : od; ix[r] = sw ? ci : oi;
    cv = sw ? od : cv;  ci = sw ? oi : ci;
  }
}

// ---------------------------------------------------------------------------
// 64-D kNN pass: fused fp32 GEMM + top-20 selection.
// Grid: (64 query-blocks, 16 candidate-chunks) = 1024 blocks -> 3 blocks/CU
// (LDS-limited: 3x48KB <= 160KB). 256 threads, __launch_bounds__(256,2):
// ROUND-7: (256,3) forced VGPR cap 84 -> re-spilled (1.5 GB scratch writes,
// 2.3x slower). Keep cap at 2 waves/EU (VGPR 128, no spill) and get
// occupancy from the grid instead (round 5 was 512 blocks = 2/CU exactly).
// Block: 128 queries x 512 candidates (4 tiles of 128), K = 64.
// Every private-array access is compile-time-indexed (rule #20).
// Fragment map: thread (am = t&15, bg = (t>>4)&15) owns queries
// {4am..4am+3, 64+4am..+3} x cands {4bg..4bg+3, 64+4bg..+3}.
// Score swizzle g(row)=((row&7)^((row>>2)&7))<<2: conflict-free write+read.
// ---------------------------------------------------------------------------
#define WRITE_S(QR, BASE)                                                   \
  {                                                                         \
    const int cc = (4 * bg) & 31;                                           \
    const int jbase = cb + (QR)*32 + cc;                                    \
    _Pragma("unroll") for (int u = 0; u < 8; ++u) {                         \
      const int row = 4 * am + (u & 3) + 64 * (u >> 2);                     \
      const int gq = qb * 128 + row;                                        \
      const int sw = ((row & 7) ^ ((row >> 2) & 7)) << 2;                   \
      float w0 = fmaf(-2.f, acc[u][(BASE) + 0], sc[(BASE) + 0]);            \
      float w1 = fmaf(-2.f, acc[u][(BASE) + 1], sc[(BASE) + 1]);            \
      float w2 = fmaf(-2.f, acc[u][(BASE) + 2], sc[(BASE) + 2]);            \
      float w3 = fmaf(-2.f, acc[u][(BASE) + 3], sc[(BASE) + 3]);            \
      if (jbase + 0 == gq) w0 = INFINITY;                                   \
      if (jbase + 1 == gq) w1 = INFINITY;                                   \
      if (jbase + 2 == gq) w2 = INFINITY;                                   \
      if (jbase + 3 == gq) w3 = INFINITY;                                   \
      *(float4*)&S[row * 32 + (cc ^ sw)] = make_float4(w0, w1, w2, w3);     \
    }                                                                       \
  }

template <int LDX>
__global__ __launch_bounds__(256, 2) void knn_gemm_kernel(
    const float* __restrict__ x, const float* __restrict__ sq,
    float* __restrict__ pd, int* __restrict__ pj) {
  __shared__ float Qs[64 * 128];   // [k][q]
  __shared__ float CsS[32 * 128];  // Cs: [k2][n] during compute; S: [q][cc]
  float* const Cs = CsS;
  float* const S = CsS;
  const int t = threadIdx.x;
  const int qb = blockIdx.x;  // 0..63
  const int ch = blockIdx.y;  // 0..15
  const int am = t & 15;
  const int bg = (t >> 4) & 15;

  // stage Q tile once: thread handles q = t&127, k-half (t>>7)*32
  {
    const int q = t & 127;
    const int k0 = (t >> 7) * 32;
    const float* src = &x[(size_t)(qb * 128 + q) * LDX + k0];
#pragma unroll
    for (int c = 0; c < 8; ++c) {
      float4 v = *(const float4*)&src[c * 4];
      Qs[(k0 + c * 4 + 0) * 128 + q] = v.x;
      Qs[(k0 + c * 4 + 1) * 128 + q] = v.y;
      Qs[(k0 + c * 4 + 2) * 128 + q] = v.z;
      Qs[(k0 + c * 4 + 3) * 128 + q] = v.w;
    }
  }

  const int selq = t & 127, part = t >> 7;
  float dreg[KNN]; int ireg[KNN];
#pragma unroll
  for (int r = 0; r < KNN; ++r) { dreg[r] = INFINITY; ireg[r] = 0x7fffffff; }

  for (int tile = 0; tile < 4; ++tile) {
    const int cb = ch * 512 + tile * 128;
    float acc[8][8] = {};
    for (int kh = 0; kh < 2; ++kh) {
      __syncthreads();  // prev S-reads / prev compute done -> CsS reusable
      {
        const int n = t & 127;
        const int k0 = (t >> 7) * 16;
        const float* src = &x[(size_t)(cb + n) * LDX + kh * 32 + k0];
#pragma unroll
        for (int c = 0; c < 4; ++c) {
          float4 v = *(const float4*)&src[c * 4];
          Cs[(k0 + c * 4 + 0) * 128 + n] = v.x;
          Cs[(k0 + c * 4 + 1) * 128 + n] = v.y;
          Cs[(k0 + c * 4 + 2) * 128 + n] = v.z;
          Cs[(k0 + c * 4 + 3) * 128 + n] = v.w;
        }
      }
      __syncthreads();
#pragma unroll 4
      for (int k2 = 0; k2 < 32; ++k2) {
        const int k = kh * 32 + k2;
        float4 A0 = *(const float4*)&Qs[k * 128 + 4 * am];
        float4 A1 = *(const float4*)&Qs[k * 128 + 4 * am + 64];
        float4 B0 = *(const float4*)&Cs[k2 * 128 + 4 * bg];
        float4 B1 = *(const float4*)&Cs[k2 * 128 + 4 * bg + 64];
        float a[8] = {A0.x, A0.y, A0.z, A0.w, A1.x, A1.y, A1.z, A1.w};
        float b[8] = {B0.x, B0.y, B0.z, B0.w, B1.x, B1.y, B1.z, B1.w};
#pragma unroll
        for (int u = 0; u < 8; ++u)
#pragma unroll
          for (int v = 0; v < 8; ++v) acc[u][v] = fmaf(a[u], b[v], acc[u][v]);
      }
    }
    // sq for my 8 candidates (compile-time indexed everywhere below)
    float4 s0 = *(const float4*)&sq[cb + 4 * bg];
    float4 s1 = *(const float4*)&sq[cb + 4 * bg + 64];
    float sc[8] = {s0.x, s0.y, s0.z, s0.w, s1.x, s1.y, s1.z, s1.w};

    const int qlow = bg >> 3;  // quarter holding my low 4 candidates
    for (int qr = 0; qr < 4; ++qr) {
      __syncthreads();  // S free (prev phase read / compute done)
      if (qr == qlow) WRITE_S(qr, 0);          // acc[u][0..3], literal base
      if (qr == 2 + qlow) WRITE_S(qr, 4);      // acc[u][4..7], literal base
      __syncthreads();
      const int swr = ((selq & 7) ^ ((selq >> 2) & 7)) << 2;
      const int jb = cb + qr * 32;
#pragma unroll
      for (int g_ = 0; g_ < 4; ++g_) {
        const int cc = part * 16 + g_ * 4;
        float4 sv = *(const float4*)&S[selq * 32 + (cc ^ swr)];
        float vv[4] = {sv.x, sv.y, sv.z, sv.w};
#pragma unroll
        for (int e = 0; e < 4; ++e) {
          if (vv[e] < dreg[KNN - 1]) insert20(dreg, ireg, vv[e], jb + cc + e);
        }
      }
    }
  }
  // write partial list (32 lists: ch*2 + part)
  const int l = ch * 2 + part;
  float* pdq = pd + ((size_t)l * NPTS + (qb * 128 + selq)) * KNN;
  int* pjq = pj + ((size_t)l * NPTS + (qb * 128 + selq)) * KNN;
#pragma unroll
  for (int r = 0; r < KNN; ++r) { pdq[r] = dreg[r]; pjq[r] = ireg[r]; }
}

// ---------------------------------------------------------------------------
// 3-D kNN pass: thread-per-query streaming over LDS candidate tiles.
// Grid: (32 query-blocks, 16 chunks), 256 threads. 16 partial lists.
// ---------------------------------------------------------------------------
__global__ __launch_bounds__(256) void knn_d3_kernel(
    const float* __restrict__ x, const float* __restrict__ sq,
    float* __restrict__ pd, int* __restrict__ pj) {
  __shared__ float4 Ct[256];  // {x, y, z, sq}
  const int t = threadIdx.x;
  const int q = blockIdx.x * 256 + t;
  const int ch = blockIdx.y;
  const float xi0 = x[q * 3], xi1 = x[q * 3 + 1], xi2 = x[q * 3 + 2];
  float dreg[KNN]; int ireg[KNN];
#pragma unroll
  for (int r = 0; r < KNN; ++r) { dreg[r] = INFINITY; ireg[r] = 0x7fffffff; }

  for (int tile = 0; tile < 2; ++tile) {
    const int cb = ch * 512 + tile * 256;
    __syncthreads();
    Ct[t] = make_float4(x[(cb + t) * 3], x[(cb + t) * 3 + 1],
                        x[(cb + t) * 3 + 2], sq[cb + t]);
    __syncthreads();
#pragma unroll 1
    for (int c = 0; c < 256; ++c) {
      float4 cv = Ct[c];
      int j = cb + c;
      float val = fmaf(-2.f, xi0 * cv.x + xi1 * cv.y + xi2 * cv.z, cv.w);
      if (j != q && val < dreg[KNN - 1]) insert20(dreg, ireg, val, j);
    }
  }
  float* pdq = pd + ((size_t)ch * NPTS + q) * KNN;
  int* pjq = pj + ((size_t)ch * NPTS + q) * KNN;
#pragma unroll
  for (int r = 0; r < KNN; ++r) { pdq[r] = dreg[r]; pjq[r] = ireg[r]; }
}

// ---------------------------------------------------------------------------
// merge L partial top-20 lists per query -> final 20 indices
// ---------------------------------------------------------------------------
__global__ __launch_bounds__(128) void knn_merge_kernel(
    const float* __restrict__ pd, const int* __restrict__ pj,
    int* __restrict__ idx_out, int L) {
  const int q = blockIdx.x * 128 + threadIdx.x;
  float d[KNN]; int ix[KNN];
#pragma unroll
  for (int r = 0; r < KNN; ++r) { d[r] = INFINITY; ix[r] = 0x7fffffff; }
#pragma unroll 1
  for (int l = 0; l < L; ++l) {
    const float* pdq = pd + ((size_t)l * NPTS + q) * KNN;
    const int* pjq = pj + ((size_t)l * NPTS + q) * KNN;
#pragma unroll 1
    for (int r = 0; r < KNN; ++r) {
      float val = pdq[r]; int j = pjq[r];
      bool worse = (val > d[KNN - 1]) ||
                   (val == d[KNN - 1] && j > ix[KNN - 1]);
      if (!worse) insert20t(d, ix, val, j);
    }
  }
#pragma unroll
  for (int r = 0; r < KNN; ++r) idx_out[(size_t)q * KNN + r] = ix[r];
}

// ---------------------------------------------------------------------------
// edge conv: out[i][c] = max_k relu(b + [x_i, x_j-x_i] . W1[:,c])
// 4 points per 256-thread block (1-wave blocks cap waves/CU at block-slots).
// ---------------------------------------------------------------------------
__global__ __launch_bounds__(256) void edgeconv_kernel(
    const float* __restrict__ x, const int* __restrict__ idx,
    const float* __restrict__ W1, const float* __restrict__ b1,
    float* __restrict__ out) {
  const int i = blockIdx.x * 4 + (threadIdx.x >> 6);
  const int c = threadIdx.x & 63;
  float w0 = W1[c], w1 = W1[64 + c], w2 = W1[128 + c];
  float w3 = W1[192 + c], w4 = W1[256 + c], w5 = W1[320 + c];
  float xi0 = x[3 * i], xi1 = x[3 * i + 1], xi2 = x[3 * i + 2];
  float base = b1[c] + xi0 * w0 + xi1 * w1 + xi2 * w2;
  float m = -INFINITY;
#pragma unroll
  for (int k = 0; k < KNN; ++k) {
    int j = idx[i * KNN + k];
    float d0 = x[3 * j] - xi0, d1 = x[3 * j + 1] - xi1, d2 = x[3 * j + 2] - xi2;
    float h = base + d0 * w3 + d1 * w4 + d2 * w5;
    m = fmaxf(m, fmaxf(h, 0.f));
  }
  out[(size_t)i * 64 + c] = m;
}

// ---------------------------------------------------------------------------
// dilate: dil[c] = max_k xin[idx[k]][c]; out = relu(dil.W + b) - xin
// 4 points per 256-thread block.
// ---------------------------------------------------------------------------
__global__ __launch_bounds__(256) void dilate_kernel(
    const float* __restrict__ xin, int ldin, const int* __restrict__ idx,
    const float* __restrict__ W, const float* __restrict__ bias,
    float* __restrict__ out, int ldout) {
  const int g = threadIdx.x >> 6;
  const int i = blockIdx.x * 4 + g;
  const int c = threadIdx.x & 63;
  __shared__ float dil[4][64];
  float m = -INFINITY;
#pragma unroll
  for (int k = 0; k < KNN; ++k) {
    int j = idx[i * KNN + k];
    m = fmaxf(m, xin[(size_t)j * ldin + c]);
  }
  dil[g][c] = m;
  __syncthreads();
  float acc = bias[c];
#pragma unroll
  for (int d = 0; d < 64; ++d) acc = fmaf(dil[g][d], W[d * 64 + c], acc);
  out[(size_t)i * ldout + c] = fmaxf(acc, 0.f) - xin[(size_t)i * ldin + c];
}

// ---------------------------------------------------------------------------
// BM=128 x BN tile fp32 GEMM, 256 threads, 8x(BN/16)/thread, relu epilogue.
// BN = 128 or 64. Requires M%128==0, N%BN==0, K%16==0.
// ---------------------------------------------------------------------------
template <int BN>
__global__ __launch_bounds__(256) void gemm128_kernel(
    const float* __restrict__ A, int K, int ldA, const float* __restrict__ W,
    int N, const float* __restrict__ bias, float* __restrict__ C, int ldC,
    int relu) {
  constexpr int VN = BN / 16;  // cands per thread (8 or 4)
  __shared__ float As[16 * 128];  // [k][m]
  __shared__ float Bs[16 * BN];   // [k][n]
  const int t = threadIdx.x;
  const int bn = blockIdx.x * BN;
  const int bm = blockIdx.y * 128;
  const int am = t & 15;
  const int bg = (t >> 4) & 15;
  float acc[8][VN] = {};

  for (int k0 = 0; k0 < K; k0 += 16) {
    __syncthreads();
    {  // A: thread loads 8 k-floats of row m = t&127
      const int m = t & 127;
      const int ka = (t >> 7) * 8;
      const float* src = &A[(size_t)(bm + m) * ldA + k0 + ka];
      float4 v0 = *(const float4*)&src[0];
      float4 v1 = *(const float4*)&src[4];
      As[(ka + 0) * 128 + m] = v0.x;
      As[(ka + 1) * 128 + m] = v0.y;
      As[(ka + 2) * 128 + m] = v0.z;
      As[(ka + 3) * 128 + m] = v0.w;
      As[(ka + 4) * 128 + m] = v1.x;
      As[(ka + 5) * 128 + m] = v1.y;
      As[(ka + 6) * 128 + m] = v1.z;
      As[(ka + 7) * 128 + m] = v1.w;
    }
    if constexpr (BN == 128) {  // B: 16k x 128n, 8 floats/thread
      const int kb = t >> 4;
      const int n8 = (t & 15) * 8;
      const float* src = &W[(size_t)(k0 + kb) * N + bn + n8];
      float4 v0 = *(const float4*)&src[0];
      float4 v1 = *(const float4*)&src[4];
      *(float4*)&Bs[kb * BN + n8] = v0;
      *(float4*)&Bs[kb * BN + n8 + 4] = v1;
    } else {  // BN == 64: 16k x 64n, 4 floats/thread
      const int kb = t >> 4;
      const int n4 = (t & 15) * 4;
      const float* src = &W[(size_t)(k0 + kb) * N + bn + n4];
      *(float4*)&Bs[kb * BN + n4] = *(const float4*)&src[0];
    }
    __syncthreads();
#pragma unroll
    for (int k = 0; k < 16; ++k) {
      float4 A0 = *(const float4*)&As[k * 128 + 4 * am];
      float4 A1 = *(const float4*)&As[k * 128 + 4 * am + 64];
      float a[8] = {A0.x, A0.y, A0.z, A0.w, A1.x, A1.y, A1.z, A1.w};
      float b[VN];
      float4 B0 = *(const float4*)&Bs[k * BN + 4 * bg];
      b[0] = B0.x; b[1] = B0.y; b[2] = B0.z; b[3] = B0.w;
      if constexpr (BN == 128) {
        float4 B1 = *(const float4*)&Bs[k * BN + 4 * bg + 64];
        b[4] = B1.x; b[5] = B1.y; b[6] = B1.z; b[7] = B1.w;
      }
#pragma unroll
      for (int u = 0; u < 8; ++u)
#pragma unroll
        for (int v = 0; v < VN; ++v) acc[u][v] = fmaf(a[u], b[v], acc[u][v]);
    }
  }
#pragma unroll
  for (int u = 0; u < 8; ++u) {
    const int m = bm + 4 * am + (u & 3) + 64 * (u >> 2);
#pragma unroll
    for (int vq = 0; vq < VN / 4; ++vq) {
      const int n = bn + 4 * bg + 64 * vq;
      float4 o;
      float* po = (float*)&o;
#pragma unroll
      for (int e = 0; e < 4; ++e) {
        float val = acc[u][vq * 4 + e] + bias[n + e];
        po[e] = relu ? fmaxf(val, 0.f) : val;
      }
      *(float4*)&C[(size_t)m * ldC + n] = o;
    }
  }
}

// ---------------------------------------------------------------------------
// logits = h3 @ Wm3 + bm3 ; out = log_softmax(logits)
// ---------------------------------------------------------------------------
__global__ __launch_bounds__(256) void final_kernel(
    const float* __restrict__ h3, const float* __restrict__ Wm3,
    const float* __restrict__ bm3, float* __restrict__ out) {
  __shared__ float hs[16][132];
  const int tid = threadIdx.x;
  const int r = tid >> 4, c = tid & 15;
  const int row0 = blockIdx.x * 16;
#pragma unroll
  for (int l = tid; l < 2048; l += 256)
    hs[l >> 7][l & 127] = h3[(size_t)row0 * 128 + l];
  __syncthreads();
  float acc = bm3[c];
#pragma unroll
  for (int d = 0; d < 128; ++d) acc = fmaf(hs[r][d], Wm3[d * 16 + c], acc);
  float mx = acc;
#pragma unroll
  for (int o = 8; o >= 1; o >>= 1) mx = fmaxf(mx, __shfl_xor(mx, o, 16));
  float e = expf(acc - mx);
  float s = e;
#pragma unroll
  for (int o = 8; o >= 1; o >>= 1) s += __shfl_xor(s, o, 16);
  out[(size_t)(row0 + r) * 16 + c] = (acc - mx) - logf(s);
}

// ---------------------------------------------------------------------------
extern "C" void kernel_launch(void* const* d_in, const int* in_sizes, int n_in,
                              void* d_out, int out_size, void* d_ws,
                              size_t ws_size, hipStream_t stream) {
  const float* x = (const float*)d_in[0];
  const float* W1 = (const float*)d_in[1];
  const float* b1 = (const float*)d_in[2];
  const float* Wd1 = (const float*)d_in[3];
  const float* bd1 = (const float*)d_in[4];
  const float* Wd2 = (const float*)d_in[5];
  const float* bd2 = (const float*)d_in[6];
  const float* Wd3 = (const float*)d_in[7];
  const float* bd3 = (const float*)d_in[8];
  const float* Wl = (const float*)d_in[9];
  const float* bl = (const float*)d_in[10];
  const float* Wm1 = (const float*)d_in[11];
  const float* bm1 = (const float*)d_in[12];
  const float* Wm2 = (const float*)d_in[13];
  const float* bm2 = (const float*)d_in[14];
  const float* Wm3 = (const float*)d_in[15];
  const float* bm3 = (const float*)d_in[16];
  float* out = (float*)d_out;

  char* ws = (char*)d_ws;
  float* sq = (float*)(ws + 0);              // 32 KB
  int* idxA = (int*)(ws + 32768);            // 640 KB
  float* xfeat = (float*)(ws + 1343488);     // 2 MB   [8192 x 64]
  float* xcat = (float*)(ws + 3440640);      // 6 MB   [8192 x 192]
  float* h1 = (float*)(ws + 9732096);        // 32 MB  [8192 x 1024]
  float* h2 = (float*)(ws + 43286528);       // 8 MB   [8192 x 256]
  float* h3 = (float*)(ws + 51675136);       // 4 MB   [8192 x 128]
  float* x1 = xcat;
  float* x2 = xcat + 64;
  float* x3 = xcat + 128;
  // partial knn lists (32 lists) live in the h1/h2 region (free until the
  // head GEMMs): pd 21 MB + pj 21 MB = [9732096, 51675136) -- ends at h3.
  float* pd = h1;
  int* pj = (int*)(ws + 9732096 + 32 * NPTS * KNN * 4);

  // stage 1: edge conv on xyz
  sqnorm_kernel<<<32, 256, 0, stream>>>(x, 3, 3, sq);
  knn_d3_kernel<<<dim3(32, 16), 256, 0, stream>>>(x, sq, pd, pj);
  knn_merge_kernel<<<64, 128, 0, stream>>>(pd, pj, idxA, 16);
  edgeconv_kernel<<<NPTS / 4, 256, 0, stream>>>(x, idxA, W1, b1, xfeat);

  // stage 2: three dilate blocks (kNN in 64-D feature space each)
  sqnorm_kernel<<<32, 256, 0, stream>>>(xfeat, 64, 64, sq);
  knn_gemm_kernel<64><<<dim3(64, 16), 256, 0, stream>>>(xfeat, sq, pd, pj);
  knn_merge_kernel<<<64, 128, 0, stream>>>(pd, pj, idxA, 32);
  dilate_kernel<<<NPTS / 4, 256, 0, stream>>>(xfeat, 64, idxA, Wd1, bd1, x1,
                                              192);

  sqnorm_kernel<<<32, 256, 0, stream>>>(x1, 192, 64, sq);
  knn_gemm_kernel<192><<<dim3(64, 16), 256, 0, stream>>>(x1, sq, pd, pj);
  knn_merge_kernel<<<64, 128, 0, stream>>>(pd, pj, idxA, 32);
  dilate_kernel<<<NPTS / 4, 256, 0, stream>>>(x1, 192, idxA, Wd2, bd2, x2,
                                              192);

  sqnorm_kernel<<<32, 256, 0, stream>>>(x2, 192, 64, sq);
  knn_gemm_kernel<192><<<dim3(64, 16), 256, 0, stream>>>(x2, sq, pd, pj);
  knn_merge_kernel<<<64, 128, 0, stream>>>(pd, pj, idxA, 32);
  dilate_kernel<<<NPTS / 4, 256, 0, stream>>>(x2, 192, idxA, Wd3, bd3, x3,
                                              192);

  // stage 3: MLP head
  gemm128_kernel<128><<<dim3(1024 / 128, NPTS / 128), 256, 0, stream>>>(
      xcat, 192, 192, Wl, 1024, bl, h1, 1024, 1);
  gemm128_kernel<64><<<dim3(256 / 64, NPTS / 128), 256, 0, stream>>>(
      h1, 1024, 1024, Wm1, 256, bm1, h2, 256, 1);
  gemm128_kernel<64><<<dim3(128 / 64, NPTS / 128), 256, 0, stream>>>(
      h2, 256, 256, Wm2, 128, bm2, h3, 128, 1);
  final_kernel<<<NPTS / 16, 256, 0, stream>>>(h3, Wm3, bm3, out);
}

// Round 8
// 1896.837 us; speedup vs baseline: 2.5082x; 1.5556x over previous
//
#include <hip/hip_runtime.h>
#include <math.h>

#define NPTS 8192
#define KNN 20

// ---------------------------------------------------------------------------
// sq[i] = sum_d x[i][d]^2
// ---------------------------------------------------------------------------
__global__ void sqnorm_kernel(const float* __restrict__ x, int ldx, int D,
                              float* __restrict__ sq) {
  int i = blockIdx.x * blockDim.x + threadIdx.x;
  if (i >= NPTS) return;
  const float* xr = x + (size_t)i * ldx;
  float s = 0.f;
  for (int d = 0; d < D; ++d) { float v = xr[d]; s += v * v; }
  sq[i] = s;
}

// ---------------------------------------------------------------------------
// Branchless sorted-insert (ascending). Caller guards with val < d[19].
// Strict < keeps earlier-scanned (smaller j) entries ahead on ties.
// All indices compile-time (full unroll) -> stays in VGPRs (rule #20).
// ---------------------------------------------------------------------------
__device__ __forceinline__ void insert20(float (&d)[KNN], int (&ix)[KNN],
                                         float val, int j) {
  float cv = val; int ci = j;
#pragma unroll
  for (int r = 0; r < KNN; ++r) {
    bool sw = cv < d[r];
    float od = d[r]; int oi = ix[r];
    d[r] = sw ? cv : od; ix[r] = sw ? ci : oi;
    cv = sw ? od : cv;  ci = sw ? oi : ci;
  }
}

// ---------------------------------------------------------------------------
// 64-D kNN pass: fused fp32 GEMM + top-20 selection. (frozen from round 7:
// VALUBusy 63%, no spill; selection-bound.)
// Grid: (64 query-blocks, 16 candidate-chunks) = 1024 blocks -> 3 blocks/CU.
// ---------------------------------------------------------------------------
#define WRITE_S(QR, BASE)                                                   \
  {                                                                         \
    const int cc = (4 * bg) & 31;                                           \
    const int jbase = cb + (QR)*32 + cc;                                    \
    _Pragma("unroll") for (int u = 0; u < 8; ++u) {                         \
      const int row = 4 * am + (u & 3) + 64 * (u >> 2);                     \
      const int gq = qb * 128 + row;                                        \
      const int sw = ((row & 7) ^ ((row >> 2) & 7)) << 2;                   \
      float w0 = fmaf(-2.f, acc[u][(BASE) + 0], sc[(BASE) + 0]);            \
      float w1 = fmaf(-2.f, acc[u][(BASE) + 1], sc[(BASE) + 1]);            \
      float w2 = fmaf(-2.f, acc[u][(BASE) + 2], sc[(BASE) + 2]);            \
      float w3 = fmaf(-2.f, acc[u][(BASE) + 3], sc[(BASE) + 3]);            \
      if (jbase + 0 == gq) w0 = INFINITY;                                   \
      if (jbase + 1 == gq) w1 = INFINITY;                                   \
      if (jbase + 2 == gq) w2 = INFINITY;                                   \
      if (jbase + 3 == gq) w3 = INFINITY;                                   \
      *(float4*)&S[row * 32 + (cc ^ sw)] = make_float4(w0, w1, w2, w3);     \
    }                                                                       \
  }

template <int LDX>
__global__ __launch_bounds__(256, 2) void knn_gemm_kernel(
    const float* __restrict__ x, const float* __restrict__ sq,
    float* __restrict__ pd, int* __restrict__ pj) {
  __shared__ float Qs[64 * 128];   // [k][q]
  __shared__ float CsS[32 * 128];  // Cs: [k2][n] during compute; S: [q][cc]
  float* const Cs = CsS;
  float* const S = CsS;
  const int t = threadIdx.x;
  const int qb = blockIdx.x;  // 0..63
  const int ch = blockIdx.y;  // 0..15
  const int am = t & 15;
  const int bg = (t >> 4) & 15;

  // stage Q tile once: thread handles q = t&127, k-half (t>>7)*32
  {
    const int q = t & 127;
    const int k0 = (t >> 7) * 32;
    const float* src = &x[(size_t)(qb * 128 + q) * LDX + k0];
#pragma unroll
    for (int c = 0; c < 8; ++c) {
      float4 v = *(const float4*)&src[c * 4];
      Qs[(k0 + c * 4 + 0) * 128 + q] = v.x;
      Qs[(k0 + c * 4 + 1) * 128 + q] = v.y;
      Qs[(k0 + c * 4 + 2) * 128 + q] = v.z;
      Qs[(k0 + c * 4 + 3) * 128 + q] = v.w;
    }
  }

  const int selq = t & 127, part = t >> 7;
  float dreg[KNN]; int ireg[KNN];
#pragma unroll
  for (int r = 0; r < KNN; ++r) { dreg[r] = INFINITY; ireg[r] = 0x7fffffff; }

  for (int tile = 0; tile < 4; ++tile) {
    const int cb = ch * 512 + tile * 128;
    float acc[8][8] = {};
    for (int kh = 0; kh < 2; ++kh) {
      __syncthreads();  // prev S-reads / prev compute done -> CsS reusable
      {
        const int n = t & 127;
        const int k0 = (t >> 7) * 16;
        const float* src = &x[(size_t)(cb + n) * LDX + kh * 32 + k0];
#pragma unroll
        for (int c = 0; c < 4; ++c) {
          float4 v = *(const float4*)&src[c * 4];
          Cs[(k0 + c * 4 + 0) * 128 + n] = v.x;
          Cs[(k0 + c * 4 + 1) * 128 + n] = v.y;
          Cs[(k0 + c * 4 + 2) * 128 + n] = v.z;
          Cs[(k0 + c * 4 + 3) * 128 + n] = v.w;
        }
      }
      __syncthreads();
#pragma unroll 4
      for (int k2 = 0; k2 < 32; ++k2) {
        const int k = kh * 32 + k2;
        float4 A0 = *(const float4*)&Qs[k * 128 + 4 * am];
        float4 A1 = *(const float4*)&Qs[k * 128 + 4 * am + 64];
        float4 B0 = *(const float4*)&Cs[k2 * 128 + 4 * bg];
        float4 B1 = *(const float4*)&Cs[k2 * 128 + 4 * bg + 64];
        float a[8] = {A0.x, A0.y, A0.z, A0.w, A1.x, A1.y, A1.z, A1.w};
        float b[8] = {B0.x, B0.y, B0.z, B0.w, B1.x, B1.y, B1.z, B1.w};
#pragma unroll
        for (int u = 0; u < 8; ++u)
#pragma unroll
          for (int v = 0; v < 8; ++v) acc[u][v] = fmaf(a[u], b[v], acc[u][v]);
      }
    }
    // sq for my 8 candidates (compile-time indexed everywhere below)
    float4 s0 = *(const float4*)&sq[cb + 4 * bg];
    float4 s1 = *(const float4*)&sq[cb + 4 * bg + 64];
    float sc[8] = {s0.x, s0.y, s0.z, s0.w, s1.x, s1.y, s1.z, s1.w};

    const int qlow = bg >> 3;  // quarter holding my low 4 candidates
    for (int qr = 0; qr < 4; ++qr) {
      __syncthreads();  // S free (prev phase read / compute done)
      if (qr == qlow) WRITE_S(qr, 0);          // acc[u][0..3], literal base
      if (qr == 2 + qlow) WRITE_S(qr, 4);      // acc[u][4..7], literal base
      __syncthreads();
      const int swr = ((selq & 7) ^ ((selq >> 2) & 7)) << 2;
      const int jb = cb + qr * 32;
#pragma unroll
      for (int g_ = 0; g_ < 4; ++g_) {
        const int cc = part * 16 + g_ * 4;
        float4 sv = *(const float4*)&S[selq * 32 + (cc ^ swr)];
        float vv[4] = {sv.x, sv.y, sv.z, sv.w};
#pragma unroll
        for (int e = 0; e < 4; ++e) {
          if (vv[e] < dreg[KNN - 1]) insert20(dreg, ireg, vv[e], jb + cc + e);
        }
      }
    }
  }
  // write partial list (32 lists: ch*2 + part), sorted (d asc, j asc)
  const int l = ch * 2 + part;
  float* pdq = pd + ((size_t)l * NPTS + (qb * 128 + selq)) * KNN;
  int* pjq = pj + ((size_t)l * NPTS + (qb * 128 + selq)) * KNN;
#pragma unroll
  for (int r = 0; r < KNN; ++r) { pdq[r] = dreg[r]; pjq[r] = ireg[r]; }
}

// ---------------------------------------------------------------------------
// 3-D kNN pass: thread-per-query over one LDS tile of 256 candidates.
// Grid: (32 query-blocks, 32 chunks), 256 threads. 32 partial lists.
// ---------------------------------------------------------------------------
__global__ __launch_bounds__(256) void knn_d3_kernel(
    const float* __restrict__ x, const float* __restrict__ sq,
    float* __restrict__ pd, int* __restrict__ pj) {
  __shared__ float4 Ct[256];  // {x, y, z, sq}
  const int t = threadIdx.x;
  const int q = blockIdx.x * 256 + t;
  const int ch = blockIdx.y;  // 0..31
  const int cb = ch * 256;
  const float xi0 = x[q * 3], xi1 = x[q * 3 + 1], xi2 = x[q * 3 + 2];
  float dreg[KNN]; int ireg[KNN];
#pragma unroll
  for (int r = 0; r < KNN; ++r) { dreg[r] = INFINITY; ireg[r] = 0x7fffffff; }

  Ct[t] = make_float4(x[(cb + t) * 3], x[(cb + t) * 3 + 1],
                      x[(cb + t) * 3 + 2], sq[cb + t]);
  __syncthreads();
#pragma unroll 1
  for (int c = 0; c < 256; ++c) {
    float4 cv = Ct[c];
    int j = cb + c;
    float val = fmaf(-2.f, xi0 * cv.x + xi1 * cv.y + xi2 * cv.z, cv.w);
    if (j != q && val < dreg[KNN - 1]) insert20(dreg, ireg, val, j);
  }
  float* pdq = pd + ((size_t)ch * NPTS + q) * KNN;
  int* pjq = pj + ((size_t)ch * NPTS + q) * KNN;
#pragma unroll
  for (int r = 0; r < KNN; ++r) { pdq[r] = dreg[r]; pjq[r] = ireg[r]; }
}

// ---------------------------------------------------------------------------
// Tournament merge of 32 SORTED partial lists per query -> final 20 indices.
// ROUND-8: replaces the serial guarded-insert merge (640 entries x ~60 VALU,
// wave-divergent guard always fires). 32 lanes = 32 lists per query, lists
// staged to LDS (runtime ptr indexing is free in LDS -- rule #20), 20 rounds
// of a 5-step shfl_xor(32) min-reduce on (d, j, srclane). Exact (d, then j)
// ordering -- identical semantics to the old insert20t merge. (d,j) pairs
// are unique across lists (streams partition candidates), so the winner is
// unique and exactly one lane advances its pointer.
// ---------------------------------------------------------------------------
__global__ __launch_bounds__(256) void knn_merge_kernel(
    const float* __restrict__ pd, const int* __restrict__ pj,
    int* __restrict__ idx_out) {
  __shared__ float sd[8][32][KNN];
  __shared__ int sjj[8][32][KNN];
  const int t = threadIdx.x;
  const int ql = t >> 5;  // 0..7 query slot
  const int l = t & 31;   // list id
  const int q = blockIdx.x * 8 + ql;
  const float* pdq = pd + ((size_t)l * NPTS + q) * KNN;
  const int* pjq = pj + ((size_t)l * NPTS + q) * KNN;
#pragma unroll
  for (int r = 0; r < KNN; ++r) { sd[ql][l][r] = pdq[r]; sjj[ql][l][r] = pjq[r]; }
  __syncthreads();
  int ptr = 0;
#pragma unroll 1
  for (int s = 0; s < KNN; ++s) {
    float d = (ptr < KNN) ? sd[ql][l][ptr] : INFINITY;
    int j = (ptr < KNN) ? sjj[ql][l][ptr] : 0x7fffffff;
    int src = l;
#pragma unroll
    for (int off = 16; off >= 1; off >>= 1) {
      float od = __shfl_xor(d, off, 32);
      int oj = __shfl_xor(j, off, 32);
      int osrc = __shfl_xor(src, off, 32);
      bool take = (od < d) || (od == d && oj < j);
      d = take ? od : d;
      j = take ? oj : j;
      src = take ? osrc : src;
    }
    if (l == src) ptr++;
    if (l == 0) idx_out[(size_t)q * KNN + s] = j;
  }
}

// ---------------------------------------------------------------------------
// edge conv: out[i][c] = max_k relu(b + [x_i, x_j-x_i] . W1[:,c])
// 4 points per 256-thread block.
// ---------------------------------------------------------------------------
__global__ __launch_bounds__(256) void edgeconv_kernel(
    const float* __restrict__ x, const int* __restrict__ idx,
    const float* __restrict__ W1, const float* __restrict__ b1,
    float* __restrict__ out) {
  const int i = blockIdx.x * 4 + (threadIdx.x >> 6);
  const int c = threadIdx.x & 63;
  float w0 = W1[c], w1 = W1[64 + c], w2 = W1[128 + c];
  float w3 = W1[192 + c], w4 = W1[256 + c], w5 = W1[320 + c];
  float xi0 = x[3 * i], xi1 = x[3 * i + 1], xi2 = x[3 * i + 2];
  float base = b1[c] + xi0 * w0 + xi1 * w1 + xi2 * w2;
  float m = -INFINITY;
#pragma unroll
  for (int k = 0; k < KNN; ++k) {
    int j = idx[i * KNN + k];
    float d0 = x[3 * j] - xi0, d1 = x[3 * j + 1] - xi1, d2 = x[3 * j + 2] - xi2;
    float h = base + d0 * w3 + d1 * w4 + d2 * w5;
    m = fmaxf(m, fmaxf(h, 0.f));
  }
  out[(size_t)i * 64 + c] = m;
}

// ---------------------------------------------------------------------------
// dilate: dil[c] = max_k xin[idx[k]][c]; out = relu(dil.W + b) - xin
// 4 points per 256-thread block.
// ---------------------------------------------------------------------------
__global__ __launch_bounds__(256) void dilate_kernel(
    const float* __restrict__ xin, int ldin, const int* __restrict__ idx,
    const float* __restrict__ W, const float* __restrict__ bias,
    float* __restrict__ out, int ldout) {
  const int g = threadIdx.x >> 6;
  const int i = blockIdx.x * 4 + g;
  const int c = threadIdx.x & 63;
  __shared__ float dil[4][64];
  float m = -INFINITY;
#pragma unroll
  for (int k = 0; k < KNN; ++k) {
    int j = idx[i * KNN + k];
    m = fmaxf(m, xin[(size_t)j * ldin + c]);
  }
  dil[g][c] = m;
  __syncthreads();
  float acc = bias[c];
#pragma unroll
  for (int d = 0; d < 64; ++d) acc = fmaf(dil[g][d], W[d * 64 + c], acc);
  out[(size_t)i * ldout + c] = fmaxf(acc, 0.f) - xin[(size_t)i * ldin + c];
}

// ---------------------------------------------------------------------------
// BM=128 x BN tile fp32 GEMM, 256 threads, 8x(BN/16)/thread, relu epilogue.
// BN = 128 or 64. Requires M%128==0, N%BN==0, K%16==0.
// ---------------------------------------------------------------------------
template <int BN>
__global__ __launch_bounds__(256) void gemm128_kernel(
    const float* __restrict__ A, int K, int ldA, const float* __restrict__ W,
    int N, const float* __restrict__ bias, float* __restrict__ C, int ldC,
    int relu) {
  constexpr int VN = BN / 16;  // cands per thread (8 or 4)
  __shared__ float As[16 * 128];  // [k][m]
  __shared__ float Bs[16 * BN];   // [k][n]
  const int t = threadIdx.x;
  const int bn = blockIdx.x * BN;
  const int bm = blockIdx.y * 128;
  const int am = t & 15;
  const int bg = (t >> 4) & 15;
  float acc[8][VN] = {};

  for (int k0 = 0; k0 < K; k0 += 16) {
    __syncthreads();
    {  // A: thread loads 8 k-floats of row m = t&127
      const int m = t & 127;
      const int ka = (t >> 7) * 8;
      const float* src = &A[(size_t)(bm + m) * ldA + k0 + ka];
      float4 v0 = *(const float4*)&src[0];
      float4 v1 = *(const float4*)&src[4];
      As[(ka + 0) * 128 + m] = v0.x;
      As[(ka + 1) * 128 + m] = v0.y;
      As[(ka + 2) * 128 + m] = v0.z;
      As[(ka + 3) * 128 + m] = v0.w;
      As[(ka + 4) * 128 + m] = v1.x;
      As[(ka + 5) * 128 + m] = v1.y;
      As[(ka + 6) * 128 + m] = v1.z;
      As[(ka + 7) * 128 + m] = v1.w;
    }
    if constexpr (BN == 128) {  // B: 16k x 128n, 8 floats/thread
      const int kb = t >> 4;
      const int n8 = (t & 15) * 8;
      const float* src = &W[(size_t)(k0 + kb) * N + bn + n8];
      float4 v0 = *(const float4*)&src[0];
      float4 v1 = *(const float4*)&src[4];
      *(float4*)&Bs[kb * BN + n8] = v0;
      *(float4*)&Bs[kb * BN + n8 + 4] = v1;
    } else {  // BN == 64: 16k x 64n, 4 floats/thread
      const int kb = t >> 4;
      const int n4 = (t & 15) * 4;
      const float* src = &W[(size_t)(k0 + kb) * N + bn + n4];
      *(float4*)&Bs[kb * BN + n4] = *(const float4*)&src[0];
    }
    __syncthreads();
#pragma unroll
    for (int k = 0; k < 16; ++k) {
      float4 A0 = *(const float4*)&As[k * 128 + 4 * am];
      float4 A1 = *(const float4*)&As[k * 128 + 4 * am + 64];
      float a[8] = {A0.x, A0.y, A0.z, A0.w, A1.x, A1.y, A1.z, A1.w};
      float b[VN];
      float4 B0 = *(const float4*)&Bs[k * BN + 4 * bg];
      b[0] = B0.x; b[1] = B0.y; b[2] = B0.z; b[3] = B0.w;
      if constexpr (BN == 128) {
        float4 B1 = *(const float4*)&Bs[k * BN + 4 * bg + 64];
        b[4] = B1.x; b[5] = B1.y; b[6] = B1.z; b[7] = B1.w;
      }
#pragma unroll
      for (int u = 0; u < 8; ++u)
#pragma unroll
        for (int v = 0; v < VN; ++v) acc[u][v] = fmaf(a[u], b[v], acc[u][v]);
    }
  }
#pragma unroll
  for (int u = 0; u < 8; ++u) {
    const int m = bm + 4 * am + (u & 3) + 64 * (u >> 2);
#pragma unroll
    for (int vq = 0; vq < VN / 4; ++vq) {
      const int n = bn + 4 * bg + 64 * vq;
      float4 o;
      float* po = (float*)&o;
#pragma unroll
      for (int e = 0; e < 4; ++e) {
        float val = acc[u][vq * 4 + e] + bias[n + e];
        po[e] = relu ? fmaxf(val, 0.f) : val;
      }
      *(float4*)&C[(size_t)m * ldC + n] = o;
    }
  }
}

// ---------------------------------------------------------------------------
// logits = h3 @ Wm3 + bm3 ; out = log_softmax(logits)
// ---------------------------------------------------------------------------
__global__ __launch_bounds__(256) void final_kernel(
    const float* __restrict__ h3, const float* __restrict__ Wm3,
    const float* __restrict__ bm3, float* __restrict__ out) {
  __shared__ float hs[16][132];
  const int tid = threadIdx.x;
  const int r = tid >> 4, c = tid & 15;
  const int row0 = blockIdx.x * 16;
#pragma unroll
  for (int l = tid; l < 2048; l += 256)
    hs[l >> 7][l & 127] = h3[(size_t)row0 * 128 + l];
  __syncthreads();
  float acc = bm3[c];
#pragma unroll
  for (int d = 0; d < 128; ++d) acc = fmaf(hs[r][d], Wm3[d * 16 + c], acc);
  float mx = acc;
#pragma unroll
  for (int o = 8; o >= 1; o >>= 1) mx = fmaxf(mx, __shfl_xor(mx, o, 16));
  float e = expf(acc - mx);
  float s = e;
#pragma unroll
  for (int o = 8; o >= 1; o >>= 1) s += __shfl_xor(s, o, 16);
  out[(size_t)(row0 + r) * 16 + c] = (acc - mx) - logf(s);
}

// ---------------------------------------------------------------------------
extern "C" void kernel_launch(void* const* d_in, const int* in_sizes, int n_in,
                              void* d_out, int out_size, void* d_ws,
                              size_t ws_size, hipStream_t stream) {
  const float* x = (const float*)d_in[0];
  const float* W1 = (const float*)d_in[1];
  const float* b1 = (const float*)d_in[2];
  const float* Wd1 = (const float*)d_in[3];
  const float* bd1 = (const float*)d_in[4];
  const float* Wd2 = (const float*)d_in[5];
  const float* bd2 = (const float*)d_in[6];
  const float* Wd3 = (const float*)d_in[7];
  const float* bd3 = (const float*)d_in[8];
  const float* Wl = (const float*)d_in[9];
  const float* bl = (const float*)d_in[10];
  const float* Wm1 = (const float*)d_in[11];
  const float* bm1 = (const float*)d_in[12];
  const float* Wm2 = (const float*)d_in[13];
  const float* bm2 = (const float*)d_in[14];
  const float* Wm3 = (const float*)d_in[15];
  const float* bm3 = (const float*)d_in[16];
  float* out = (float*)d_out;

  char* ws = (char*)d_ws;
  float* sq = (float*)(ws + 0);              // 32 KB
  int* idxA = (int*)(ws + 32768);            // 640 KB
  float* xfeat = (float*)(ws + 1343488);     // 2 MB   [8192 x 64]
  float* xcat = (float*)(ws + 3440640);      // 6 MB   [8192 x 192]
  float* h1 = (float*)(ws + 9732096);        // 32 MB  [8192 x 1024]
  float* h2 = (float*)(ws + 43286528);       // 8 MB   [8192 x 256]
  float* h3 = (float*)(ws + 51675136);       // 4 MB   [8192 x 128]
  float* x1 = xcat;
  float* x2 = xcat + 64;
  float* x3 = xcat + 128;
  // partial knn lists (32 lists) live in the h1/h2 region (free until the
  // head GEMMs): pd 21 MB + pj 21 MB = [9732096, 51675136) -- ends at h3.
  float* pd = h1;
  int* pj = (int*)(ws + 9732096 + 32 * NPTS * KNN * 4);

  // stage 1: edge conv on xyz
  sqnorm_kernel<<<32, 256, 0, stream>>>(x, 3, 3, sq);
  knn_d3_kernel<<<dim3(32, 32), 256, 0, stream>>>(x, sq, pd, pj);
  knn_merge_kernel<<<NPTS / 8, 256, 0, stream>>>(pd, pj, idxA);
  edgeconv_kernel<<<NPTS / 4, 256, 0, stream>>>(x, idxA, W1, b1, xfeat);

  // stage 2: three dilate blocks (kNN in 64-D feature space each)
  sqnorm_kernel<<<32, 256, 0, stream>>>(xfeat, 64, 64, sq);
  knn_gemm_kernel<64><<<dim3(64, 16), 256, 0, stream>>>(xfeat, sq, pd, pj);
  knn_merge_kernel<<<NPTS / 8, 256, 0, stream>>>(pd, pj, idxA);
  dilate_kernel<<<NPTS / 4, 256, 0, stream>>>(xfeat, 64, idxA, Wd1, bd1, x1,
                                              192);

  sqnorm_kernel<<<32, 256, 0, stream>>>(x1, 192, 64, sq);
  knn_gemm_kernel<192><<<dim3(64, 16), 256, 0, stream>>>(x1, sq, pd, pj);
  knn_merge_kernel<<<NPTS / 8, 256, 0, stream>>>(pd, pj, idxA);
  dilate_kernel<<<NPTS / 4, 256, 0, stream>>>(x1, 192, idxA, Wd2, bd2, x2,
                                              192);

  sqnorm_kernel<<<32, 256, 0, stream>>>(x2, 192, 64, sq);
  knn_gemm_kernel<192><<<dim3(64, 16), 256, 0, stream>>>(x2, sq, pd, pj);
  knn_merge_kernel<<<NPTS / 8, 256, 0, stream>>>(pd, pj, idxA);
  dilate_kernel<<<NPTS / 4, 256, 0, stream>>>(x2, 192, idxA, Wd3, bd3, x3,
                                              192);

  // stage 3: MLP head
  gemm128_kernel<128><<<dim3(1024 / 128, NPTS / 128), 256, 0, stream>>>(
      xcat, 192, 192, Wl, 1024, bl, h1, 1024, 1);
  gemm128_kernel<64><<<dim3(256 / 64, NPTS / 128), 256, 0, stream>>>(
      h1, 1024, 1024, Wm1, 256, bm1, h2, 256, 1);
  gemm128_kernel<64><<<dim3(128 / 64, NPTS / 128), 256, 0, stream>>>(
      h2, 256, 256, Wm2, 128, bm2, h3, 128, 1);
  final_kernel<<<NPTS / 16, 256, 0, stream>>>(h3, Wm3, bm3, out);
}

// Round 9
// 1700.441 us; speedup vs baseline: 2.7979x; 1.1155x over previous
//
#include <hip/hip_runtime.h>
#include <math.h>

#define NPTS 8192
#define KNN 20

// monotonic u32 key: a<b (float, incl. inf) <=> fkey(a)<fkey(b)
__device__ __forceinline__ uint32_t fkey(float v) {
  uint32_t b = __float_as_uint(v);
  return b ^ ((uint32_t)((int)b >> 31) | 0x80000000u);
}

// ---------------------------------------------------------------------------
// sq[i] = sum_d x[i][d]^2
// ---------------------------------------------------------------------------
__global__ void sqnorm_kernel(const float* __restrict__ x, int ldx, int D,
                              float* __restrict__ sq) {
  int i = blockIdx.x * blockDim.x + threadIdx.x;
  if (i >= NPTS) return;
  const float* xr = x + (size_t)i * ldx;
  float s = 0.f;
  for (int d = 0; d < D; ++d) { float v = xr[d]; s += v * v; }
  sq[i] = s;
}

// ---------------------------------------------------------------------------
// (d3 path only) branchless sorted-insert with index, ascending; strict <
// keeps earlier-scanned (smaller j) entries ahead on ties.
// ---------------------------------------------------------------------------
__device__ __forceinline__ void insert20(float (&d)[KNN], int (&ix)[KNN],
                                         float val, int j) {
  float cv = val; int ci = j;
#pragma unroll
  for (int r = 0; r < KNN; ++r) {
    bool sw = cv < d[r];
    float od = d[r]; int oi = ix[r];
    d[r] = sw ? cv : od; ix[r] = sw ? ci : oi;
    cv = sw ? od : cv;  ci = sw ? oi : ci;
  }
}

// ---------------------------------------------------------------------------
// 64-D kNN pass 1: fused fp32 GEMM + DISTANCE-ONLY top-20 (u32 keys).
// Round-9: drop index tracking in the hot ripple -- v_min_u32/v_max_u32,
// 2 ops/step vs 5 (insert20 carried dist+idx). Indices recovered in a second
// GEMM pass against the exact per-query 20th key T_q (bit-identical fmaf
// chain -> bit-identical keys).
// Grid: (64 query-blocks, 16 chunks), 256 threads, 48 KB LDS, (256,2).
// ---------------------------------------------------------------------------
#define WRITE_S(QR, BASE)                                                   \
  {                                                                         \
    const int cc = (4 * bg) & 31;                                           \
    const int jbase = cb + (QR)*32 + cc;                                    \
    _Pragma("unroll") for (int u = 0; u < 8; ++u) {                         \
      const int row = 4 * am + (u & 3) + 64 * (u >> 2);                     \
      const int gq = qb * 128 + row;                                        \
      const int sw = ((row & 7) ^ ((row >> 2) & 7)) << 2;                   \
      uint32_t k0 = fkey(fmaf(-2.f, acc[u][(BASE) + 0], sc[(BASE) + 0]));   \
      uint32_t k1 = fkey(fmaf(-2.f, acc[u][(BASE) + 1], sc[(BASE) + 1]));   \
      uint32_t k2 = fkey(fmaf(-2.f, acc[u][(BASE) + 2], sc[(BASE) + 2]));   \
      uint32_t k3 = fkey(fmaf(-2.f, acc[u][(BASE) + 3], sc[(BASE) + 3]));   \
      if (jbase + 0 == gq) k0 = 0xFFFFFFFFu;                                \
      if (jbase + 1 == gq) k1 = 0xFFFFFFFFu;                                \
      if (jbase + 2 == gq) k2 = 0xFFFFFFFFu;                                \
      if (jbase + 3 == gq) k3 = 0xFFFFFFFFu;                                \
      *(uint4*)&S[row * 32 + (cc ^ sw)] = make_uint4(k0, k1, k2, k3);       \
    }                                                                       \
  }

template <int LDX>
__global__ __launch_bounds__(256, 2) void knn_gemm_kernel(
    const float* __restrict__ x, const float* __restrict__ sq,
    uint32_t* __restrict__ pk) {
  __shared__ float Qs[64 * 128];      // [k][q]
  __shared__ uint32_t CsS[32 * 128];  // Cs floats during compute; S keys
  float* const Cs = (float*)CsS;
  uint32_t* const S = CsS;
  const int t = threadIdx.x;
  const int qb = blockIdx.x;  // 0..63
  const int ch = blockIdx.y;  // 0..15
  const int am = t & 15;
  const int bg = (t >> 4) & 15;

  {
    const int q = t & 127;
    const int k0 = (t >> 7) * 32;
    const float* src = &x[(size_t)(qb * 128 + q) * LDX + k0];
#pragma unroll
    for (int c = 0; c < 8; ++c) {
      float4 v = *(const float4*)&src[c * 4];
      Qs[(k0 + c * 4 + 0) * 128 + q] = v.x;
      Qs[(k0 + c * 4 + 1) * 128 + q] = v.y;
      Qs[(k0 + c * 4 + 2) * 128 + q] = v.z;
      Qs[(k0 + c * 4 + 3) * 128 + q] = v.w;
    }
  }

  const int selq = t & 127, part = t >> 7;
  uint32_t dreg[KNN];
#pragma unroll
  for (int r = 0; r < KNN; ++r) dreg[r] = 0xFFFFFFFFu;

  for (int tile = 0; tile < 4; ++tile) {
    const int cb = ch * 512 + tile * 128;
    float acc[8][8] = {};
    for (int kh = 0; kh < 2; ++kh) {
      __syncthreads();
      {
        const int n = t & 127;
        const int k0 = (t >> 7) * 16;
        const float* src = &x[(size_t)(cb + n) * LDX + kh * 32 + k0];
#pragma unroll
        for (int c = 0; c < 4; ++c) {
          float4 v = *(const float4*)&src[c * 4];
          Cs[(k0 + c * 4 + 0) * 128 + n] = v.x;
          Cs[(k0 + c * 4 + 1) * 128 + n] = v.y;
          Cs[(k0 + c * 4 + 2) * 128 + n] = v.z;
          Cs[(k0 + c * 4 + 3) * 128 + n] = v.w;
        }
      }
      __syncthreads();
#pragma unroll 4
      for (int k2 = 0; k2 < 32; ++k2) {
        const int k = kh * 32 + k2;
        float4 A0 = *(const float4*)&Qs[k * 128 + 4 * am];
        float4 A1 = *(const float4*)&Qs[k * 128 + 4 * am + 64];
        float4 B0 = *(const float4*)&Cs[k2 * 128 + 4 * bg];
        float4 B1 = *(const float4*)&Cs[k2 * 128 + 4 * bg + 64];
        float a[8] = {A0.x, A0.y, A0.z, A0.w, A1.x, A1.y, A1.z, A1.w};
        float b[8] = {B0.x, B0.y, B0.z, B0.w, B1.x, B1.y, B1.z, B1.w};
#pragma unroll
        for (int u = 0; u < 8; ++u)
#pragma unroll
          for (int v = 0; v < 8; ++v) acc[u][v] = fmaf(a[u], b[v], acc[u][v]);
      }
    }
    float4 s0 = *(const float4*)&sq[cb + 4 * bg];
    float4 s1 = *(const float4*)&sq[cb + 4 * bg + 64];
    float sc[8] = {s0.x, s0.y, s0.z, s0.w, s1.x, s1.y, s1.z, s1.w};

    const int qlow = bg >> 3;
    for (int qr = 0; qr < 4; ++qr) {
      __syncthreads();
      if (qr == qlow) WRITE_S(qr, 0);
      if (qr == 2 + qlow) WRITE_S(qr, 4);
      __syncthreads();
      const int swr = ((selq & 7) ^ ((selq >> 2) & 7)) << 2;
#pragma unroll
      for (int g_ = 0; g_ < 4; ++g_) {
        const int cc = part * 16 + g_ * 4;
        uint4 sv = *(const uint4*)&S[selq * 32 + (cc ^ swr)];
        uint32_t kv[4] = {sv.x, sv.y, sv.z, sv.w};
#pragma unroll
        for (int e = 0; e < 4; ++e) {
          uint32_t kk = kv[e];
          if (kk < dreg[KNN - 1]) {
            uint32_t cv = kk;
#pragma unroll
            for (int r = 0; r < KNN; ++r) {
              uint32_t nd = min(dreg[r], cv);
              cv = max(dreg[r], cv);
              dreg[r] = nd;
            }
          }
        }
      }
    }
  }
  // sorted 20 keys per (list = ch*2+part, query)
  const int l = ch * 2 + part;
  uint32_t* pkq = pk + ((size_t)l * NPTS + (qb * 128 + selq)) * KNN;
#pragma unroll
  for (int r = 0; r < KNN; ++r) pkq[r] = dreg[r];
}

// ---------------------------------------------------------------------------
// Tournament over 32 sorted key-lists -> T[q] = exact 20th-smallest key.
// ---------------------------------------------------------------------------
__global__ __launch_bounds__(256) void knn_mergeT_kernel(
    const uint32_t* __restrict__ pk, uint32_t* __restrict__ T) {
  __shared__ uint32_t sk[8][32][KNN];
  const int t = threadIdx.x;
  const int ql = t >> 5;
  const int l = t & 31;
  const int q = blockIdx.x * 8 + ql;
  const uint32_t* pkq = pk + ((size_t)l * NPTS + q) * KNN;
#pragma unroll
  for (int r = 0; r < KNN; ++r) sk[ql][l][r] = pkq[r];
  __syncthreads();
  int ptr = 0;
  uint32_t k = 0;
#pragma unroll 1
  for (int s = 0; s < KNN; ++s) {
    k = (ptr < KNN) ? sk[ql][l][ptr] : 0xFFFFFFFFu;
    int src = l;
#pragma unroll
    for (int off = 16; off >= 1; off >>= 1) {
      uint32_t ok = __shfl_xor(k, off, 32);
      int osrc = __shfl_xor(src, off, 32);
      bool take = (ok < k) || (ok == k && osrc < src);
      k = take ? ok : k;
      src = take ? osrc : src;
    }
    if (l == src) ptr++;
  }
  if (l == 0) T[q] = k;  // 20th pop
}

// ---------------------------------------------------------------------------
// Recovery: GEMM clone (bit-identical fmaf chain), no S phases; compact all
// (key <= T_q) candidates via atomicAdd into 64-slot per-query buffers.
// Self-match packs to fkey(inf) > any finite T -> auto-excluded.
// ---------------------------------------------------------------------------
template <int LDX>
__global__ __launch_bounds__(256, 2) void knn_recover_kernel(
    const float* __restrict__ x, const float* __restrict__ sq,
    const uint32_t* __restrict__ T, uint32_t* __restrict__ cnt,
    uint32_t* __restrict__ cd, int* __restrict__ cj) {
  __shared__ float Qs[64 * 128];
  __shared__ float Cs[32 * 128];
  const int t = threadIdx.x;
  const int qb = blockIdx.x;
  const int ch = blockIdx.y;
  const int am = t & 15;
  const int bg = (t >> 4) & 15;

  {
    const int q = t & 127;
    const int k0 = (t >> 7) * 32;
    const float* src = &x[(size_t)(qb * 128 + q) * LDX + k0];
#pragma unroll
    for (int c = 0; c < 8; ++c) {
      float4 v = *(const float4*)&src[c * 4];
      Qs[(k0 + c * 4 + 0) * 128 + q] = v.x;
      Qs[(k0 + c * 4 + 1) * 128 + q] = v.y;
      Qs[(k0 + c * 4 + 2) * 128 + q] = v.z;
      Qs[(k0 + c * 4 + 3) * 128 + q] = v.w;
    }
  }
  uint32_t Tq[8];
#pragma unroll
  for (int u = 0; u < 8; ++u)
    Tq[u] = T[qb * 128 + 4 * am + (u & 3) + 64 * (u >> 2)];

  for (int tile = 0; tile < 4; ++tile) {
    const int cb = ch * 512 + tile * 128;
    float acc[8][8] = {};
    for (int kh = 0; kh < 2; ++kh) {
      __syncthreads();
      {
        const int n = t & 127;
        const int k0 = (t >> 7) * 16;
        const float* src = &x[(size_t)(cb + n) * LDX + kh * 32 + k0];
#pragma unroll
        for (int c = 0; c < 4; ++c) {
          float4 v = *(const float4*)&src[c * 4];
          Cs[(k0 + c * 4 + 0) * 128 + n] = v.x;
          Cs[(k0 + c * 4 + 1) * 128 + n] = v.y;
          Cs[(k0 + c * 4 + 2) * 128 + n] = v.z;
          Cs[(k0 + c * 4 + 3) * 128 + n] = v.w;
        }
      }
      __syncthreads();
#pragma unroll 4
      for (int k2 = 0; k2 < 32; ++k2) {
        const int k = kh * 32 + k2;
        float4 A0 = *(const float4*)&Qs[k * 128 + 4 * am];
        float4 A1 = *(const float4*)&Qs[k * 128 + 4 * am + 64];
        float4 B0 = *(const float4*)&Cs[k2 * 128 + 4 * bg];
        float4 B1 = *(const float4*)&Cs[k2 * 128 + 4 * bg + 64];
        float a[8] = {A0.x, A0.y, A0.z, A0.w, A1.x, A1.y, A1.z, A1.w};
        float b[8] = {B0.x, B0.y, B0.z, B0.w, B1.x, B1.y, B1.z, B1.w};
#pragma unroll
        for (int u = 0; u < 8; ++u)
#pragma unroll
          for (int v = 0; v < 8; ++v) acc[u][v] = fmaf(a[u], b[v], acc[u][v]);
      }
    }
    float4 s0 = *(const float4*)&sq[cb + 4 * bg];
    float4 s1 = *(const float4*)&sq[cb + 4 * bg + 64];
    float sc[8] = {s0.x, s0.y, s0.z, s0.w, s1.x, s1.y, s1.z, s1.w};
#pragma unroll
    for (int u = 0; u < 8; ++u) {
      const int gq = qb * 128 + 4 * am + (u & 3) + 64 * (u >> 2);
#pragma unroll
      for (int v = 0; v < 8; ++v) {
        const int j = cb + 4 * bg + (v & 3) + 64 * (v >> 2);
        float val = fmaf(-2.f, acc[u][v], sc[v]);
        if (j == gq) val = INFINITY;
        uint32_t key = fkey(val);
        if (key <= Tq[u]) {
          uint32_t slot = atomicAdd(&cnt[gq], 1u);
          if (slot < 64u) {
            cd[(size_t)gq * 64 + slot] = key;
            cj[(size_t)gq * 64 + slot] = j;
          }
        }
      }
    }
  }
}

// ---------------------------------------------------------------------------
// Final select: one wave per query; 64 lanes hold the <=64 recovered (key,j);
// 20 rounds of exact (key, then j) shfl-min tournament -> indices.
// ---------------------------------------------------------------------------
__global__ __launch_bounds__(256) void knn_final_kernel(
    const uint32_t* __restrict__ cnt, const uint32_t* __restrict__ cd,
    const int* __restrict__ cj, int* __restrict__ idx_out) {
  const int t = threadIdx.x;
  const int w = t >> 6;
  const int l = t & 63;
  const int q = blockIdx.x * 4 + w;
  const int n = min(cnt[q], 64u);
  uint32_t k = (l < n) ? cd[(size_t)q * 64 + l] : 0xFFFFFFFFu;
  int j = (l < n) ? cj[(size_t)q * 64 + l] : 0x7fffffff;
#pragma unroll 1
  for (int s = 0; s < KNN; ++s) {
    uint32_t mk = k;
    int mj = j;
#pragma unroll
    for (int off = 32; off >= 1; off >>= 1) {
      uint32_t ok = __shfl_xor(mk, off, 64);
      int oj = __shfl_xor(mj, off, 64);
      bool take = (ok < mk) || (ok == mk && oj < mj);
      mk = take ? ok : mk;
      mj = take ? oj : mj;
    }
    if (k == mk && j == mj) { k = 0xFFFFFFFFu; j = 0x7fffffff; }
    if (l == 0) idx_out[(size_t)q * KNN + s] = mj;
  }
}

// ---------------------------------------------------------------------------
// 3-D kNN pass (unchanged): thread-per-query, 32 chunks, (d,j) lists.
// ---------------------------------------------------------------------------
__global__ __launch_bounds__(256) void knn_d3_kernel(
    const float* __restrict__ x, const float* __restrict__ sq,
    float* __restrict__ pd, int* __restrict__ pj) {
  __shared__ float4 Ct[256];
  const int t = threadIdx.x;
  const int q = blockIdx.x * 256 + t;
  const int ch = blockIdx.y;
  const int cb = ch * 256;
  const float xi0 = x[q * 3], xi1 = x[q * 3 + 1], xi2 = x[q * 3 + 2];
  float dreg[KNN]; int ireg[KNN];
#pragma unroll
  for (int r = 0; r < KNN; ++r) { dreg[r] = INFINITY; ireg[r] = 0x7fffffff; }

  Ct[t] = make_float4(x[(cb + t) * 3], x[(cb + t) * 3 + 1],
                      x[(cb + t) * 3 + 2], sq[cb + t]);
  __syncthreads();
#pragma unroll 1
  for (int c = 0; c < 256; ++c) {
    float4 cv = Ct[c];
    int j = cb + c;
    float val = fmaf(-2.f, xi0 * cv.x + xi1 * cv.y + xi2 * cv.z, cv.w);
    if (j != q && val < dreg[KNN - 1]) insert20(dreg, ireg, val, j);
  }
  float* pdq = pd + ((size_t)ch * NPTS + q) * KNN;
  int* pjq = pj + ((size_t)ch * NPTS + q) * KNN;
#pragma unroll
  for (int r = 0; r < KNN; ++r) { pdq[r] = dreg[r]; pjq[r] = ireg[r]; }
}

// ---------------------------------------------------------------------------
// (d3 only) tournament merge of 32 sorted (d,j) lists -> 20 indices.
// ---------------------------------------------------------------------------
__global__ __launch_bounds__(256) void knn_merge_idx_kernel(
    const float* __restrict__ pd, const int* __restrict__ pj,
    int* __restrict__ idx_out) {
  __shared__ float sd[8][32][KNN];
  __shared__ int sjj[8][32][KNN];
  const int t = threadIdx.x;
  const int ql = t >> 5;
  const int l = t & 31;
  const int q = blockIdx.x * 8 + ql;
  const float* pdq = pd + ((size_t)l * NPTS + q) * KNN;
  const int* pjq = pj + ((size_t)l * NPTS + q) * KNN;
#pragma unroll
  for (int r = 0; r < KNN; ++r) { sd[ql][l][r] = pdq[r]; sjj[ql][l][r] = pjq[r]; }
  __syncthreads();
  int ptr = 0;
#pragma unroll 1
  for (int s = 0; s < KNN; ++s) {
    float d = (ptr < KNN) ? sd[ql][l][ptr] : INFINITY;
    int j = (ptr < KNN) ? sjj[ql][l][ptr] : 0x7fffffff;
    int src = l;
#pragma unroll
    for (int off = 16; off >= 1; off >>= 1) {
      float od = __shfl_xor(d, off, 32);
      int oj = __shfl_xor(j, off, 32);
      int osrc = __shfl_xor(src, off, 32);
      bool take = (od < d) || (od == d && oj < j);
      d = take ? od : d;
      j = take ? oj : j;
      src = take ? osrc : src;
    }
    if (l == src) ptr++;
    if (l == 0) idx_out[(size_t)q * KNN + s] = j;
  }
}

// ---------------------------------------------------------------------------
// edge conv (unchanged)
// ---------------------------------------------------------------------------
__global__ __launch_bounds__(256) void edgeconv_kernel(
    const float* __restrict__ x, const int* __restrict__ idx,
    const float* __restrict__ W1, const float* __restrict__ b1,
    float* __restrict__ out) {
  const int i = blockIdx.x * 4 + (threadIdx.x >> 6);
  const int c = threadIdx.x & 63;
  float w0 = W1[c], w1 = W1[64 + c], w2 = W1[128 + c];
  float w3 = W1[192 + c], w4 = W1[256 + c], w5 = W1[320 + c];
  float xi0 = x[3 * i], xi1 = x[3 * i + 1], xi2 = x[3 * i + 2];
  float base = b1[c] + xi0 * w0 + xi1 * w1 + xi2 * w2;
  float m = -INFINITY;
#pragma unroll
  for (int k = 0; k < KNN; ++k) {
    int j = idx[i * KNN + k];
    float d0 = x[3 * j] - xi0, d1 = x[3 * j + 1] - xi1, d2 = x[3 * j + 2] - xi2;
    float h = base + d0 * w3 + d1 * w4 + d2 * w5;
    m = fmaxf(m, fmaxf(h, 0.f));
  }
  out[(size_t)i * 64 + c] = m;
}

// ---------------------------------------------------------------------------
// dilate (unchanged)
// ---------------------------------------------------------------------------
__global__ __launch_bounds__(256) void dilate_kernel(
    const float* __restrict__ xin, int ldin, const int* __restrict__ idx,
    const float* __restrict__ W, const float* __restrict__ bias,
    float* __restrict__ out, int ldout) {
  const int g = threadIdx.x >> 6;
  const int i = blockIdx.x * 4 + g;
  const int c = threadIdx.x & 63;
  __shared__ float dil[4][64];
  float m = -INFINITY;
#pragma unroll
  for (int k = 0; k < KNN; ++k) {
    int j = idx[i * KNN + k];
    m = fmaxf(m, xin[(size_t)j * ldin + c]);
  }
  dil[g][c] = m;
  __syncthreads();
  float acc = bias[c];
#pragma unroll
  for (int d = 0; d < 64; ++d) acc = fmaf(dil[g][d], W[d * 64 + c], acc);
  out[(size_t)i * ldout + c] = fmaxf(acc, 0.f) - xin[(size_t)i * ldin + c];
}

// ---------------------------------------------------------------------------
// BM=128 x BN tile fp32 GEMM (unchanged)
// ---------------------------------------------------------------------------
template <int BN>
__global__ __launch_bounds__(256) void gemm128_kernel(
    const float* __restrict__ A, int K, int ldA, const float* __restrict__ W,
    int N, const float* __restrict__ bias, float* __restrict__ C, int ldC,
    int relu) {
  constexpr int VN = BN / 16;
  __shared__ float As[16 * 128];
  __shared__ float Bs[16 * BN];
  const int t = threadIdx.x;
  const int bn = blockIdx.x * BN;
  const int bm = blockIdx.y * 128;
  const int am = t & 15;
  const int bg = (t >> 4) & 15;
  float acc[8][VN] = {};

  for (int k0 = 0; k0 < K; k0 += 16) {
    __syncthreads();
    {
      const int m = t & 127;
      const int ka = (t >> 7) * 8;
      const float* src = &A[(size_t)(bm + m) * ldA + k0 + ka];
      float4 v0 = *(const float4*)&src[0];
      float4 v1 = *(const float4*)&src[4];
      As[(ka + 0) * 128 + m] = v0.x;
      As[(ka + 1) * 128 + m] = v0.y;
      As[(ka + 2) * 128 + m] = v0.z;
      As[(ka + 3) * 128 + m] = v0.w;
      As[(ka + 4) * 128 + m] = v1.x;
      As[(ka + 5) * 128 + m] = v1.y;
      As[(ka + 6) * 128 + m] = v1.z;
      As[(ka + 7) * 128 + m] = v1.w;
    }
    if constexpr (BN == 128) {
      const int kb = t >> 4;
      const int n8 = (t & 15) * 8;
      const float* src = &W[(size_t)(k0 + kb) * N + bn + n8];
      float4 v0 = *(const float4*)&src[0];
      float4 v1 = *(const float4*)&src[4];
      *(float4*)&Bs[kb * BN + n8] = v0;
      *(float4*)&Bs[kb * BN + n8 + 4] = v1;
    } else {
      const int kb = t >> 4;
      const int n4 = (t & 15) * 4;
      const float* src = &W[(size_t)(k0 + kb) * N + bn + n4];
      *(float4*)&Bs[kb * BN + n4] = *(const float4*)&src[0];
    }
    __syncthreads();
#pragma unroll
    for (int k = 0; k < 16; ++k) {
      float4 A0 = *(const float4*)&As[k * 128 + 4 * am];
      float4 A1 = *(const float4*)&As[k * 128 + 4 * am + 64];
      float a[8] = {A0.x, A0.y, A0.z, A0.w, A1.x, A1.y, A1.z, A1.w};
      float b[VN];
      float4 B0 = *(const float4*)&Bs[k * BN + 4 * bg];
      b[0] = B0.x; b[1] = B0.y; b[2] = B0.z; b[3] = B0.w;
      if constexpr (BN == 128) {
        float4 B1 = *(const float4*)&Bs[k * BN + 4 * bg + 64];
        b[4] = B1.x; b[5] = B1.y; b[6] = B1.z; b[7] = B1.w;
      }
#pragma unroll
      for (int u = 0; u < 8; ++u)
#pragma unroll
        for (int v = 0; v < VN; ++v) acc[u][v] = fmaf(a[u], b[v], acc[u][v]);
    }
  }
#pragma unroll
  for (int u = 0; u < 8; ++u) {
    const int m = bm + 4 * am + (u & 3) + 64 * (u >> 2);
#pragma unroll
    for (int vq = 0; vq < VN / 4; ++vq) {
      const int n = bn + 4 * bg + 64 * vq;
      float4 o;
      float* po = (float*)&o;
#pragma unroll
      for (int e = 0; e < 4; ++e) {
        float val = acc[u][vq * 4 + e] + bias[n + e];
        po[e] = relu ? fmaxf(val, 0.f) : val;
      }
      *(float4*)&C[(size_t)m * ldC + n] = o;
    }
  }
}

// ---------------------------------------------------------------------------
// logits + log_softmax (unchanged)
// ---------------------------------------------------------------------------
__global__ __launch_bounds__(256) void final_kernel(
    const float* __restrict__ h3, const float* __restrict__ Wm3,
    const float* __restrict__ bm3, float* __restrict__ out) {
  __shared__ float hs[16][132];
  const int tid = threadIdx.x;
  const int r = tid >> 4, c = tid & 15;
  const int row0 = blockIdx.x * 16;
#pragma unroll
  for (int l = tid; l < 2048; l += 256)
    hs[l >> 7][l & 127] = h3[(size_t)row0 * 128 + l];
  __syncthreads();
  float acc = bm3[c];
#pragma unroll
  for (int d = 0; d < 128; ++d) acc = fmaf(hs[r][d], Wm3[d * 16 + c], acc);
  float mx = acc;
#pragma unroll
  for (int o = 8; o >= 1; o >>= 1) mx = fmaxf(mx, __shfl_xor(mx, o, 16));
  float e = expf(acc - mx);
  float s = e;
#pragma unroll
  for (int o = 8; o >= 1; o >>= 1) s += __shfl_xor(s, o, 16);
  out[(size_t)(row0 + r) * 16 + c] = (acc - mx) - logf(s);
}

// ---------------------------------------------------------------------------
extern "C" void kernel_launch(void* const* d_in, const int* in_sizes, int n_in,
                              void* d_out, int out_size, void* d_ws,
                              size_t ws_size, hipStream_t stream) {
  const float* x = (const float*)d_in[0];
  const float* W1 = (const float*)d_in[1];
  const float* b1 = (const float*)d_in[2];
  const float* Wd1 = (const float*)d_in[3];
  const float* bd1 = (const float*)d_in[4];
  const float* Wd2 = (const float*)d_in[5];
  const float* bd2 = (const float*)d_in[6];
  const float* Wd3 = (const float*)d_in[7];
  const float* bd3 = (const float*)d_in[8];
  const float* Wl = (const float*)d_in[9];
  const float* bl = (const float*)d_in[10];
  const float* Wm1 = (const float*)d_in[11];
  const float* bm1 = (const float*)d_in[12];
  const float* Wm2 = (const float*)d_in[13];
  const float* bm2 = (const float*)d_in[14];
  const float* Wm3 = (const float*)d_in[15];
  const float* bm3 = (const float*)d_in[16];
  float* out = (float*)d_out;

  char* ws = (char*)d_ws;
  float* sq = (float*)(ws + 0);              // 32 KB
  int* idxA = (int*)(ws + 32768);            // 640 KB
  float* xfeat = (float*)(ws + 1343488);     // 2 MB   [8192 x 64]
  float* xcat = (float*)(ws + 3440640);      // 6 MB   [8192 x 192]
  float* h1 = (float*)(ws + 9732096);        // 32 MB  [8192 x 1024]
  float* h2 = (float*)(ws + 43286528);       // 8 MB   [8192 x 256]
  float* h3 = (float*)(ws + 51675136);       // 4 MB   [8192 x 128]
  float* x1 = xcat;
  float* x2 = xcat + 64;
  float* x3 = xcat + 128;
  // knn scratch in the h1/h2 region (free until the head GEMMs):
  //   pk/pd: 32 lists x NPTS x 20 x 4B = 21 MB  at 9732096
  //   pj (d3) : 21 MB at 30703616 -- aliased after d3 by T/cnt/cd/cj
  uint32_t* pk = (uint32_t*)(ws + 9732096);
  float* pd = (float*)pk;
  int* pj = (int*)(ws + 30703616);
  uint32_t* T = (uint32_t*)(ws + 30703616);             // 32 KB
  uint32_t* cnt = (uint32_t*)(ws + 30703616 + 32768);   // 32 KB
  uint32_t* cd = (uint32_t*)(ws + 30703616 + 65536);    // 2 MB
  int* cj = (int*)(ws + 30703616 + 65536 + 2097152);    // 2 MB

  // stage 1: edge conv on xyz (exact (d,j) path)
  sqnorm_kernel<<<32, 256, 0, stream>>>(x, 3, 3, sq);
  knn_d3_kernel<<<dim3(32, 32), 256, 0, stream>>>(x, sq, pd, pj);
  knn_merge_idx_kernel<<<NPTS / 8, 256, 0, stream>>>(pd, pj, idxA);
  edgeconv_kernel<<<NPTS / 4, 256, 0, stream>>>(x, idxA, W1, b1, xfeat);

  // stage 2: three dilate blocks; 64-D kNN = keys pass + merge-T + recover
#define KNN64_PASS(XIN, LDX)                                                 \
  sqnorm_kernel<<<32, 256, 0, stream>>>(XIN, LDX, 64, sq);                   \
  hipMemsetAsync(cnt, 0, NPTS * 4, stream);                                  \
  knn_gemm_kernel<LDX><<<dim3(64, 16), 256, 0, stream>>>(XIN, sq, pk);       \
  knn_mergeT_kernel<<<NPTS / 8, 256, 0, stream>>>(pk, T);                    \
  knn_recover_kernel<LDX><<<dim3(64, 16), 256, 0, stream>>>(XIN, sq, T, cnt, \
                                                            cd, cj);         \
  knn_final_kernel<<<NPTS / 4, 256, 0, stream>>>(cnt, cd, cj, idxA);

  KNN64_PASS(xfeat, 64)
  dilate_kernel<<<NPTS / 4, 256, 0, stream>>>(xfeat, 64, idxA, Wd1, bd1, x1,
                                              192);
  KNN64_PASS(x1, 192)
  dilate_kernel<<<NPTS / 4, 256, 0, stream>>>(x1, 192, idxA, Wd2, bd2, x2,
                                              192);
  KNN64_PASS(x2, 192)
  dilate_kernel<<<NPTS / 4, 256, 0, stream>>>(x2, 192, idxA, Wd3, bd3, x3,
                                              192);
#undef KNN64_PASS

  // stage 3: MLP head
  gemm128_kernel<128><<<dim3(1024 / 128, NPTS / 128), 256, 0, stream>>>(
      xcat, 192, 192, Wl, 1024, bl, h1, 1024, 1);
  gemm128_kernel<64><<<dim3(256 / 64, NPTS / 128), 256, 0, stream>>>(
      h1, 1024, 1024, Wm1, 256, bm1, h2, 256, 1);
  gemm128_kernel<64><<<dim3(128 / 64, NPTS / 128), 256, 0, stream>>>(
      h2, 256, 256, Wm2, 128, bm2, h3, 128, 1);
  final_kernel<<<NPTS / 16, 256, 0, stream>>>(h3, Wm3, bm3, out);
}

// Round 10
// 1393.736 us; speedup vs baseline: 3.4135x; 1.2201x over previous
//
#include <hip/hip_runtime.h>
#include <math.h>

#define NPTS 8192
#define KNN 20
#define CAP 256

// monotonic u32 key: a<b (float, incl. inf) <=> fkey(a)<fkey(b)
__device__ __forceinline__ uint32_t fkey(float v) {
  uint32_t b = __float_as_uint(v);
  return b ^ ((uint32_t)((int)b >> 31) | 0x80000000u);
}

// key-only sorted-insert: 2 VALU/step (v_min_u32/v_max_u32)
__device__ __forceinline__ void insert20k(uint32_t (&d)[KNN], uint32_t key) {
#pragma unroll
  for (int r = 0; r < KNN; ++r) {
    uint32_t nd = min(d[r], key);
    key = max(d[r], key);
    d[r] = nd;
  }
}

// ---------------------------------------------------------------------------
// sq[i] = sum_d x[i][d]^2
// ---------------------------------------------------------------------------
__global__ void sqnorm_kernel(const float* __restrict__ x, int ldx, int D,
                              float* __restrict__ sq) {
  int i = blockIdx.x * blockDim.x + threadIdx.x;
  if (i >= NPTS) return;
  const float* xr = x + (size_t)i * ldx;
  float s = 0.f;
  for (int d = 0; d < D; ++d) { float v = xr[d]; s += v * v; }
  sq[i] = s;
}

// ---------------------------------------------------------------------------
// 64-D kNN approx pass: fused fp32 GEMM + key-only top-20 over the HALF
// subset (candidates 0..4095). T~ = 20th of a subset >= exact 20th, so the
// recover+final path stays exact; survivors ~40/query, cap 256 (P(overflow)
// ~ e^-90). Grid: (64 query-blocks, 16 chunks of 256 cands) = 1024 blocks
// -> 3 blocks/CU. 32 sorted key-lists (ch*2+part) of the subset.
// ---------------------------------------------------------------------------
#define WRITE_S(QR, BASE)                                                   \
  {                                                                         \
    const int cc = (4 * bg) & 31;                                           \
    const int jbase = cb + (QR)*32 + cc;                                    \
    _Pragma("unroll") for (int u = 0; u < 8; ++u) {                         \
      const int row = 4 * am + (u & 3) + 64 * (u >> 2);                     \
      const int gq = qb * 128 + row;                                        \
      const int sw = ((row & 7) ^ ((row >> 2) & 7)) << 2;                   \
      uint32_t k0 = fkey(fmaf(-2.f, acc[u][(BASE) + 0], sc[(BASE) + 0]));   \
      uint32_t k1 = fkey(fmaf(-2.f, acc[u][(BASE) + 1], sc[(BASE) + 1]));   \
      uint32_t k2 = fkey(fmaf(-2.f, acc[u][(BASE) + 2], sc[(BASE) + 2]));   \
      uint32_t k3 = fkey(fmaf(-2.f, acc[u][(BASE) + 3], sc[(BASE) + 3]));   \
      if (jbase + 0 == gq) k0 = 0xFFFFFFFFu;                                \
      if (jbase + 1 == gq) k1 = 0xFFFFFFFFu;                                \
      if (jbase + 2 == gq) k2 = 0xFFFFFFFFu;                                \
      if (jbase + 3 == gq) k3 = 0xFFFFFFFFu;                                \
      *(uint4*)&S[row * 32 + (cc ^ sw)] = make_uint4(k0, k1, k2, k3);       \
    }                                                                       \
  }

template <int LDX>
__global__ __launch_bounds__(256, 2) void knn_gemm_kernel(
    const float* __restrict__ x, const float* __restrict__ sq,
    uint32_t* __restrict__ pk) {
  __shared__ float Qs[64 * 128];      // [k][q]
  __shared__ uint32_t CsS[32 * 128];  // Cs floats during compute; S keys
  float* const Cs = (float*)CsS;
  uint32_t* const S = CsS;
  const int t = threadIdx.x;
  const int qb = blockIdx.x;  // 0..63
  const int ch = blockIdx.y;  // 0..15 (subset: cands ch*256 .. ch*256+255)
  const int am = t & 15;
  const int bg = (t >> 4) & 15;

  {
    const int q = t & 127;
    const int k0 = (t >> 7) * 32;
    const float* src = &x[(size_t)(qb * 128 + q) * LDX + k0];
#pragma unroll
    for (int c = 0; c < 8; ++c) {
      float4 v = *(const float4*)&src[c * 4];
      Qs[(k0 + c * 4 + 0) * 128 + q] = v.x;
      Qs[(k0 + c * 4 + 1) * 128 + q] = v.y;
      Qs[(k0 + c * 4 + 2) * 128 + q] = v.z;
      Qs[(k0 + c * 4 + 3) * 128 + q] = v.w;
    }
  }

  const int selq = t & 127, part = t >> 7;
  uint32_t dreg[KNN];
#pragma unroll
  for (int r = 0; r < KNN; ++r) dreg[r] = 0xFFFFFFFFu;

  for (int tile = 0; tile < 2; ++tile) {
    const int cb = ch * 256 + tile * 128;
    float acc[8][8] = {};
    for (int kh = 0; kh < 2; ++kh) {
      __syncthreads();
      {
        const int n = t & 127;
        const int k0 = (t >> 7) * 16;
        const float* src = &x[(size_t)(cb + n) * LDX + kh * 32 + k0];
#pragma unroll
        for (int c = 0; c < 4; ++c) {
          float4 v = *(const float4*)&src[c * 4];
          Cs[(k0 + c * 4 + 0) * 128 + n] = v.x;
          Cs[(k0 + c * 4 + 1) * 128 + n] = v.y;
          Cs[(k0 + c * 4 + 2) * 128 + n] = v.z;
          Cs[(k0 + c * 4 + 3) * 128 + n] = v.w;
        }
      }
      __syncthreads();
#pragma unroll 4
      for (int k2 = 0; k2 < 32; ++k2) {
        const int k = kh * 32 + k2;
        float4 A0 = *(const float4*)&Qs[k * 128 + 4 * am];
        float4 A1 = *(const float4*)&Qs[k * 128 + 4 * am + 64];
        float4 B0 = *(const float4*)&Cs[k2 * 128 + 4 * bg];
        float4 B1 = *(const float4*)&Cs[k2 * 128 + 4 * bg + 64];
        float a[8] = {A0.x, A0.y, A0.z, A0.w, A1.x, A1.y, A1.z, A1.w};
        float b[8] = {B0.x, B0.y, B0.z, B0.w, B1.x, B1.y, B1.z, B1.w};
#pragma unroll
        for (int u = 0; u < 8; ++u)
#pragma unroll
          for (int v = 0; v < 8; ++v) acc[u][v] = fmaf(a[u], b[v], acc[u][v]);
      }
    }
    float4 s0 = *(const float4*)&sq[cb + 4 * bg];
    float4 s1 = *(const float4*)&sq[cb + 4 * bg + 64];
    float sc[8] = {s0.x, s0.y, s0.z, s0.w, s1.x, s1.y, s1.z, s1.w};

    const int qlow = bg >> 3;
    for (int qr = 0; qr < 4; ++qr) {
      __syncthreads();
      if (qr == qlow) WRITE_S(qr, 0);
      if (qr == 2 + qlow) WRITE_S(qr, 4);
      __syncthreads();
      const int swr = ((selq & 7) ^ ((selq >> 2) & 7)) << 2;
#pragma unroll
      for (int g_ = 0; g_ < 4; ++g_) {
        const int cc = part * 16 + g_ * 4;
        uint4 sv = *(const uint4*)&S[selq * 32 + (cc ^ swr)];
        uint32_t kv[4] = {sv.x, sv.y, sv.z, sv.w};
#pragma unroll
        for (int e = 0; e < 4; ++e) {
          if (kv[e] < dreg[KNN - 1]) insert20k(dreg, kv[e]);
        }
      }
    }
  }
  const int l = ch * 2 + part;  // 32 lists
  uint32_t* pkq = pk + ((size_t)l * NPTS + (qb * 128 + selq)) * KNN;
#pragma unroll
  for (int r = 0; r < KNN; ++r) pkq[r] = dreg[r];
}

// ---------------------------------------------------------------------------
// Tournament over 32 sorted key-lists -> T[q] = 20th-smallest subset key.
// ---------------------------------------------------------------------------
__global__ __launch_bounds__(256) void knn_mergeT_kernel(
    const uint32_t* __restrict__ pk, uint32_t* __restrict__ T) {
  __shared__ uint32_t sk[8][32][KNN];
  const int t = threadIdx.x;
  const int ql = t >> 5;
  const int l = t & 31;
  const int q = blockIdx.x * 8 + ql;
  const uint32_t* pkq = pk + ((size_t)l * NPTS + q) * KNN;
#pragma unroll
  for (int r = 0; r < KNN; ++r) sk[ql][l][r] = pkq[r];
  __syncthreads();
  int ptr = 0;
  uint32_t k = 0;
#pragma unroll 1
  for (int s = 0; s < KNN; ++s) {
    k = (ptr < KNN) ? sk[ql][l][ptr] : 0xFFFFFFFFu;
    int src = l;
#pragma unroll
    for (int off = 16; off >= 1; off >>= 1) {
      uint32_t ok = __shfl_xor(k, off, 32);
      int osrc = __shfl_xor(src, off, 32);
      bool take = (ok < k) || (ok == k && osrc < src);
      k = take ? ok : k;
      src = take ? osrc : src;
    }
    if (l == src) ptr++;
  }
  if (l == 0) T[q] = k;  // 20th pop
}

// ---------------------------------------------------------------------------
// 64-D recovery: GEMM clone over ALL candidates; compact key <= T~ into
// CAP-slot per-query buffers. Self packs to fkey(inf) > T~ -> excluded.
// ---------------------------------------------------------------------------
template <int LDX>
__global__ __launch_bounds__(256, 2) void knn_recover_kernel(
    const float* __restrict__ x, const float* __restrict__ sq,
    const uint32_t* __restrict__ T, uint32_t* __restrict__ cnt,
    uint32_t* __restrict__ cd, int* __restrict__ cj) {
  __shared__ float Qs[64 * 128];
  __shared__ float Cs[32 * 128];
  const int t = threadIdx.x;
  const int qb = blockIdx.x;
  const int ch = blockIdx.y;  // 0..15, full range: cands ch*512..+511
  const int am = t & 15;
  const int bg = (t >> 4) & 15;

  {
    const int q = t & 127;
    const int k0 = (t >> 7) * 32;
    const float* src = &x[(size_t)(qb * 128 + q) * LDX + k0];
#pragma unroll
    for (int c = 0; c < 8; ++c) {
      float4 v = *(const float4*)&src[c * 4];
      Qs[(k0 + c * 4 + 0) * 128 + q] = v.x;
      Qs[(k0 + c * 4 + 1) * 128 + q] = v.y;
      Qs[(k0 + c * 4 + 2) * 128 + q] = v.z;
      Qs[(k0 + c * 4 + 3) * 128 + q] = v.w;
    }
  }
  uint32_t Tq[8];
#pragma unroll
  for (int u = 0; u < 8; ++u)
    Tq[u] = T[qb * 128 + 4 * am + (u & 3) + 64 * (u >> 2)];

  for (int tile = 0; tile < 4; ++tile) {
    const int cb = ch * 512 + tile * 128;
    float acc[8][8] = {};
    for (int kh = 0; kh < 2; ++kh) {
      __syncthreads();
      {
        const int n = t & 127;
        const int k0 = (t >> 7) * 16;
        const float* src = &x[(size_t)(cb + n) * LDX + kh * 32 + k0];
#pragma unroll
        for (int c = 0; c < 4; ++c) {
          float4 v = *(const float4*)&src[c * 4];
          Cs[(k0 + c * 4 + 0) * 128 + n] = v.x;
          Cs[(k0 + c * 4 + 1) * 128 + n] = v.y;
          Cs[(k0 + c * 4 + 2) * 128 + n] = v.z;
          Cs[(k0 + c * 4 + 3) * 128 + n] = v.w;
        }
      }
      __syncthreads();
#pragma unroll 4
      for (int k2 = 0; k2 < 32; ++k2) {
        const int k = kh * 32 + k2;
        float4 A0 = *(const float4*)&Qs[k * 128 + 4 * am];
        float4 A1 = *(const float4*)&Qs[k * 128 + 4 * am + 64];
        float4 B0 = *(const float4*)&Cs[k2 * 128 + 4 * bg];
        float4 B1 = *(const float4*)&Cs[k2 * 128 + 4 * bg + 64];
        float a[8] = {A0.x, A0.y, A0.z, A0.w, A1.x, A1.y, A1.z, A1.w};
        float b[8] = {B0.x, B0.y, B0.z, B0.w, B1.x, B1.y, B1.z, B1.w};
#pragma unroll
        for (int u = 0; u < 8; ++u)
#pragma unroll
          for (int v = 0; v < 8; ++v) acc[u][v] = fmaf(a[u], b[v], acc[u][v]);
      }
    }
    float4 s0 = *(const float4*)&sq[cb + 4 * bg];
    float4 s1 = *(const float4*)&sq[cb + 4 * bg + 64];
    float sc[8] = {s0.x, s0.y, s0.z, s0.w, s1.x, s1.y, s1.z, s1.w};
#pragma unroll
    for (int u = 0; u < 8; ++u) {
      const int gq = qb * 128 + 4 * am + (u & 3) + 64 * (u >> 2);
#pragma unroll
      for (int v = 0; v < 8; ++v) {
        const int j = cb + 4 * bg + (v & 3) + 64 * (v >> 2);
        float val = fmaf(-2.f, acc[u][v], sc[v]);
        if (j == gq) val = INFINITY;
        uint32_t key = fkey(val);
        if (key <= Tq[u]) {
          uint32_t slot = atomicAdd(&cnt[gq], 1u);
          if (slot < (uint32_t)CAP) {
            cd[(size_t)gq * CAP + slot] = key;
            cj[(size_t)gq * CAP + slot] = j;
          }
        }
      }
    }
  }
}

// ---------------------------------------------------------------------------
// 3-D approx pass: key-only top-20 over HALF subset (cands 0..4095),
// 32 chunks of 128 staged in LDS. Grid (32, 32), 256 threads.
// ---------------------------------------------------------------------------
__global__ __launch_bounds__(256) void knn_d3k_kernel(
    const float* __restrict__ x, const float* __restrict__ sq,
    uint32_t* __restrict__ pk) {
  __shared__ float4 Ct[128];
  const int t = threadIdx.x;
  const int q = blockIdx.x * 256 + t;
  const int ch = blockIdx.y;  // 0..31
  const int cb = ch * 128;
  if (t < 128)
    Ct[t] = make_float4(x[(cb + t) * 3], x[(cb + t) * 3 + 1],
                        x[(cb + t) * 3 + 2], sq[cb + t]);
  const float xi0 = x[q * 3], xi1 = x[q * 3 + 1], xi2 = x[q * 3 + 2];
  uint32_t dreg[KNN];
#pragma unroll
  for (int r = 0; r < KNN; ++r) dreg[r] = 0xFFFFFFFFu;
  __syncthreads();
#pragma unroll 1
  for (int c = 0; c < 128; ++c) {
    float4 cv = Ct[c];
    int j = cb + c;
    float val = fmaf(-2.f, xi0 * cv.x + xi1 * cv.y + xi2 * cv.z, cv.w);
    uint32_t key = fkey(val);
    if (j != q && key < dreg[KNN - 1]) insert20k(dreg, key);
  }
  uint32_t* pkq = pk + ((size_t)ch * NPTS + q) * KNN;
#pragma unroll
  for (int r = 0; r < KNN; ++r) pkq[r] = dreg[r];
}

// ---------------------------------------------------------------------------
// 3-D recovery: stream all 8192 candidates, compact key <= T~.
// Grid (32, 32 chunks of 256), 256 threads.
// ---------------------------------------------------------------------------
__global__ __launch_bounds__(256) void knn_d3_recover_kernel(
    const float* __restrict__ x, const float* __restrict__ sq,
    const uint32_t* __restrict__ T, uint32_t* __restrict__ cnt,
    uint32_t* __restrict__ cd, int* __restrict__ cj) {
  __shared__ float4 Ct[256];
  const int t = threadIdx.x;
  const int q = blockIdx.x * 256 + t;
  const int ch = blockIdx.y;
  const int cb = ch * 256;
  Ct[t] = make_float4(x[(cb + t) * 3], x[(cb + t) * 3 + 1],
                      x[(cb + t) * 3 + 2], sq[cb + t]);
  const float xi0 = x[q * 3], xi1 = x[q * 3 + 1], xi2 = x[q * 3 + 2];
  const uint32_t Tq = T[q];
  __syncthreads();
#pragma unroll 1
  for (int c = 0; c < 256; ++c) {
    float4 cv = Ct[c];
    int j = cb + c;
    float val = fmaf(-2.f, xi0 * cv.x + xi1 * cv.y + xi2 * cv.z, cv.w);
    uint32_t key = fkey(val);
    if (j != q && key <= Tq) {
      uint32_t slot = atomicAdd(&cnt[q], 1u);
      if (slot < (uint32_t)CAP) {
        cd[(size_t)q * CAP + slot] = key;
        cj[(size_t)q * CAP + slot] = j;
      }
    }
  }
}

// ---------------------------------------------------------------------------
// Final select: one wave per query over <=CAP survivors. Lane holds 4
// entries sorted by (key,j) in regs; 20 rounds of 6-step shfl tournament,
// winner lane shift-pops (all static indexing). Exact lax.top_k tie order.
// ---------------------------------------------------------------------------
#define CSWAP(ka, ja, kb, jb)                                   \
  {                                                             \
    bool sw = (kb < ka) || (kb == ka && jb < ja);               \
    uint32_t tk = sw ? kb : ka; int tj = sw ? jb : ja;          \
    kb = sw ? ka : kb; jb = sw ? ja : jb;                       \
    ka = tk; ja = tj;                                           \
  }

__global__ __launch_bounds__(256) void knn_final_kernel(
    const uint32_t* __restrict__ cnt, const uint32_t* __restrict__ cd,
    const int* __restrict__ cj, int* __restrict__ idx_out) {
  const int t = threadIdx.x;
  const int w = t >> 6;
  const int l = t & 63;
  const int q = blockIdx.x * 4 + w;
  const int n = (int)min(cnt[q], (uint32_t)CAP);
  uint32_t k0 = 0xFFFFFFFFu, k1 = 0xFFFFFFFFu, k2 = 0xFFFFFFFFu,
           k3 = 0xFFFFFFFFu;
  int j0 = 0x7fffffff, j1 = 0x7fffffff, j2 = 0x7fffffff, j3 = 0x7fffffff;
  if (l < n) { k0 = cd[(size_t)q * CAP + l]; j0 = cj[(size_t)q * CAP + l]; }
  if (l + 64 < n) { k1 = cd[(size_t)q * CAP + l + 64]; j1 = cj[(size_t)q * CAP + l + 64]; }
  if (l + 128 < n) { k2 = cd[(size_t)q * CAP + l + 128]; j2 = cj[(size_t)q * CAP + l + 128]; }
  if (l + 192 < n) { k3 = cd[(size_t)q * CAP + l + 192]; j3 = cj[(size_t)q * CAP + l + 192]; }
  CSWAP(k0, j0, k1, j1); CSWAP(k2, j2, k3, j3);
  CSWAP(k0, j0, k2, j2); CSWAP(k1, j1, k3, j3);
  CSWAP(k1, j1, k2, j2);
#pragma unroll 1
  for (int s = 0; s < KNN; ++s) {
    uint32_t mk = k0;
    int mj = j0;
#pragma unroll
    for (int off = 32; off >= 1; off >>= 1) {
      uint32_t ok = __shfl_xor(mk, off, 64);
      int oj = __shfl_xor(mj, off, 64);
      bool take = (ok < mk) || (ok == mk && oj < mj);
      mk = take ? ok : mk;
      mj = take ? oj : mj;
    }
    if (k0 == mk && j0 == mj) {  // unique: j distinct per query
      k0 = k1; j0 = j1; k1 = k2; j1 = j2; k2 = k3; j2 = j3;
      k3 = 0xFFFFFFFFu; j3 = 0x7fffffff;
    }
    if (l == 0) idx_out[(size_t)q * KNN + s] = mj;
  }
}

// ---------------------------------------------------------------------------
// edge conv (unchanged)
// ---------------------------------------------------------------------------
__global__ __launch_bounds__(256) void edgeconv_kernel(
    const float* __restrict__ x, const int* __restrict__ idx,
    const float* __restrict__ W1, const float* __restrict__ b1,
    float* __restrict__ out) {
  const int i = blockIdx.x * 4 + (threadIdx.x >> 6);
  const int c = threadIdx.x & 63;
  float w0 = W1[c], w1 = W1[64 + c], w2 = W1[128 + c];
  float w3 = W1[192 + c], w4 = W1[256 + c], w5 = W1[320 + c];
  float xi0 = x[3 * i], xi1 = x[3 * i + 1], xi2 = x[3 * i + 2];
  float base = b1[c] + xi0 * w0 + xi1 * w1 + xi2 * w2;
  float m = -INFINITY;
#pragma unroll
  for (int k = 0; k < KNN; ++k) {
    int j = idx[i * KNN + k];
    float d0 = x[3 * j] - xi0, d1 = x[3 * j + 1] - xi1, d2 = x[3 * j + 2] - xi2;
    float h = base + d0 * w3 + d1 * w4 + d2 * w5;
    m = fmaxf(m, fmaxf(h, 0.f));
  }
  out[(size_t)i * 64 + c] = m;
}

// ---------------------------------------------------------------------------
// dilate (unchanged)
// ---------------------------------------------------------------------------
__global__ __launch_bounds__(256) void dilate_kernel(
    const float* __restrict__ xin, int ldin, const int* __restrict__ idx,
    const float* __restrict__ W, const float* __restrict__ bias,
    float* __restrict__ out, int ldout) {
  const int g = threadIdx.x >> 6;
  const int i = blockIdx.x * 4 + g;
  const int c = threadIdx.x & 63;
  __shared__ float dil[4][64];
  float m = -INFINITY;
#pragma unroll
  for (int k = 0; k < KNN; ++k) {
    int j = idx[i * KNN + k];
    m = fmaxf(m, xin[(size_t)j * ldin + c]);
  }
  dil[g][c] = m;
  __syncthreads();
  float acc = bias[c];
#pragma unroll
  for (int d = 0; d < 64; ++d) acc = fmaf(dil[g][d], W[d * 64 + c], acc);
  out[(size_t)i * ldout + c] = fmaxf(acc, 0.f) - xin[(size_t)i * ldin + c];
}

// ---------------------------------------------------------------------------
// BM=128 x BN tile fp32 GEMM (unchanged)
// ---------------------------------------------------------------------------
template <int BN>
__global__ __launch_bounds__(256) void gemm128_kernel(
    const float* __restrict__ A, int K, int ldA, const float* __restrict__ W,
    int N, const float* __restrict__ bias, float* __restrict__ C, int ldC,
    int relu) {
  constexpr int VN = BN / 16;
  __shared__ float As[16 * 128];
  __shared__ float Bs[16 * BN];
  const int t = threadIdx.x;
  const int bn = blockIdx.x * BN;
  const int bm = blockIdx.y * 128;
  const int am = t & 15;
  const int bg = (t >> 4) & 15;
  float acc[8][VN] = {};

  for (int k0 = 0; k0 < K; k0 += 16) {
    __syncthreads();
    {
      const int m = t & 127;
      const int ka = (t >> 7) * 8;
      const float* src = &A[(size_t)(bm + m) * ldA + k0 + ka];
      float4 v0 = *(const float4*)&src[0];
      float4 v1 = *(const float4*)&src[4];
      As[(ka + 0) * 128 + m] = v0.x;
      As[(ka + 1) * 128 + m] = v0.y;
      As[(ka + 2) * 128 + m] = v0.z;
      As[(ka + 3) * 128 + m] = v0.w;
      As[(ka + 4) * 128 + m] = v1.x;
      As[(ka + 5) * 128 + m] = v1.y;
      As[(ka + 6) * 128 + m] = v1.z;
      As[(ka + 7) * 128 + m] = v1.w;
    }
    if constexpr (BN == 128) {
      const int kb = t >> 4;
      const int n8 = (t & 15) * 8;
      const float* src = &W[(size_t)(k0 + kb) * N + bn + n8];
      float4 v0 = *(const float4*)&src[0];
      float4 v1 = *(const float4*)&src[4];
      *(float4*)&Bs[kb * BN + n8] = v0;
      *(float4*)&Bs[kb * BN + n8 + 4] = v1;
    } else {
      const int kb = t >> 4;
      const int n4 = (t & 15) * 4;
      const float* src = &W[(size_t)(k0 + kb) * N + bn + n4];
      *(float4*)&Bs[kb * BN + n4] = *(const float4*)&src[0];
    }
    __syncthreads();
#pragma unroll
    for (int k = 0; k < 16; ++k) {
      float4 A0 = *(const float4*)&As[k * 128 + 4 * am];
      float4 A1 = *(const float4*)&As[k * 128 + 4 * am + 64];
      float a[8] = {A0.x, A0.y, A0.z, A0.w, A1.x, A1.y, A1.z, A1.w};
      float b[VN];
      float4 B0 = *(const float4*)&Bs[k * BN + 4 * bg];
      b[0] = B0.x; b[1] = B0.y; b[2] = B0.z; b[3] = B0.w;
      if constexpr (BN == 128) {
        float4 B1 = *(const float4*)&Bs[k * BN + 4 * bg + 64];
        b[4] = B1.x; b[5] = B1.y; b[6] = B1.z; b[7] = B1.w;
      }
#pragma unroll
      for (int u = 0; u < 8; ++u)
#pragma unroll
        for (int v = 0; v < VN; ++v) acc[u][v] = fmaf(a[u], b[v], acc[u][v]);
    }
  }
#pragma unroll
  for (int u = 0; u < 8; ++u) {
    const int m = bm + 4 * am + (u & 3) + 64 * (u >> 2);
#pragma unroll
    for (int vq = 0; vq < VN / 4; ++vq) {
      const int n = bn + 4 * bg + 64 * vq;
      float4 o;
      float* po = (float*)&o;
#pragma unroll
      for (int e = 0; e < 4; ++e) {
        float val = acc[u][vq * 4 + e] + bias[n + e];
        po[e] = relu ? fmaxf(val, 0.f) : val;
      }
      *(float4*)&C[(size_t)m * ldC + n] = o;
    }
  }
}

// ---------------------------------------------------------------------------
// logits + log_softmax (unchanged)
// ---------------------------------------------------------------------------
__global__ __launch_bounds__(256) void final_kernel(
    const float* __restrict__ h3, const float* __restrict__ Wm3,
    const float* __restrict__ bm3, float* __restrict__ out) {
  __shared__ float hs[16][132];
  const int tid = threadIdx.x;
  const int r = tid >> 4, c = tid & 15;
  const int row0 = blockIdx.x * 16;
#pragma unroll
  for (int l = tid; l < 2048; l += 256)
    hs[l >> 7][l & 127] = h3[(size_t)row0 * 128 + l];
  __syncthreads();
  float acc = bm3[c];
#pragma unroll
  for (int d = 0; d < 128; ++d) acc = fmaf(hs[r][d], Wm3[d * 16 + c], acc);
  float mx = acc;
#pragma unroll
  for (int o = 8; o >= 1; o >>= 1) mx = fmaxf(mx, __shfl_xor(mx, o, 16));
  float e = expf(acc - mx);
  float s = e;
#pragma unroll
  for (int o = 8; o >= 1; o >>= 1) s += __shfl_xor(s, o, 16);
  out[(size_t)(row0 + r) * 16 + c] = (acc - mx) - logf(s);
}

// ---------------------------------------------------------------------------
extern "C" void kernel_launch(void* const* d_in, const int* in_sizes, int n_in,
                              void* d_out, int out_size, void* d_ws,
                              size_t ws_size, hipStream_t stream) {
  const float* x = (const float*)d_in[0];
  const float* W1 = (const float*)d_in[1];
  const float* b1 = (const float*)d_in[2];
  const float* Wd1 = (const float*)d_in[3];
  const float* bd1 = (const float*)d_in[4];
  const float* Wd2 = (const float*)d_in[5];
  const float* bd2 = (const float*)d_in[6];
  const float* Wd3 = (const float*)d_in[7];
  const float* bd3 = (const float*)d_in[8];
  const float* Wl = (const float*)d_in[9];
  const float* bl = (const float*)d_in[10];
  const float* Wm1 = (const float*)d_in[11];
  const float* bm1 = (const float*)d_in[12];
  const float* Wm2 = (const float*)d_in[13];
  const float* bm2 = (const float*)d_in[14];
  const float* Wm3 = (const float*)d_in[15];
  const float* bm3 = (const float*)d_in[16];
  float* out = (float*)d_out;

  char* ws = (char*)d_ws;
  float* sq = (float*)(ws + 0);              // 32 KB
  int* idxA = (int*)(ws + 32768);            // 640 KB
  float* xfeat = (float*)(ws + 1343488);     // 2 MB   [8192 x 64]
  float* xcat = (float*)(ws + 3440640);      // 6 MB   [8192 x 192]
  float* h1 = (float*)(ws + 9732096);        // 32 MB  [8192 x 1024]
  float* h2 = (float*)(ws + 43286528);       // 8 MB   [8192 x 256]
  float* h3 = (float*)(ws + 51675136);       // 4 MB   [8192 x 128]
  float* x1 = xcat;
  float* x2 = xcat + 64;
  float* x3 = xcat + 128;
  // knn scratch in the h1/h2 region (free until the head GEMMs):
  uint32_t* pk = (uint32_t*)(ws + 9732096);            // 21 MB (32 lists)
  uint32_t* T = (uint32_t*)(ws + 30703616);            // 32 KB
  uint32_t* cnt = (uint32_t*)(ws + 30703616 + 32768);  // 32 KB
  uint32_t* cd = (uint32_t*)(ws + 30703616 + 65536);   // 8 MB (CAP=256)
  int* cj = (int*)(ws + 30703616 + 65536 + 8388608);   // 8 MB -> ends 47.5MB

  // stage 1: edge conv on xyz (approx-T + exact recover path)
  sqnorm_kernel<<<32, 256, 0, stream>>>(x, 3, 3, sq);
  hipMemsetAsync(cnt, 0, NPTS * 4, stream);
  knn_d3k_kernel<<<dim3(32, 32), 256, 0, stream>>>(x, sq, pk);
  knn_mergeT_kernel<<<NPTS / 8, 256, 0, stream>>>(pk, T);
  knn_d3_recover_kernel<<<dim3(32, 32), 256, 0, stream>>>(x, sq, T, cnt, cd,
                                                          cj);
  knn_final_kernel<<<NPTS / 4, 256, 0, stream>>>(cnt, cd, cj, idxA);
  edgeconv_kernel<<<NPTS / 4, 256, 0, stream>>>(x, idxA, W1, b1, xfeat);

  // stage 2: three dilate blocks; 64-D kNN = half-subset keys + T~ + recover
#define KNN64_PASS(XIN, LDX)                                                 \
  sqnorm_kernel<<<32, 256, 0, stream>>>(XIN, LDX, 64, sq);                   \
  hipMemsetAsync(cnt, 0, NPTS * 4, stream);                                  \
  knn_gemm_kernel<LDX><<<dim3(64, 16), 256, 0, stream>>>(XIN, sq, pk);       \
  knn_mergeT_kernel<<<NPTS / 8, 256, 0, stream>>>(pk, T);                    \
  knn_recover_kernel<LDX><<<dim3(64, 16), 256, 0, stream>>>(XIN, sq, T, cnt, \
                                                            cd, cj);         \
  knn_final_kernel<<<NPTS / 4, 256, 0, stream>>>(cnt, cd, cj, idxA);

  KNN64_PASS(xfeat, 64)
  dilate_kernel<<<NPTS / 4, 256, 0, stream>>>(xfeat, 64, idxA, Wd1, bd1, x1,
                                              192);
  KNN64_PASS(x1, 192)
  dilate_kernel<<<NPTS / 4, 256, 0, stream>>>(x1, 192, idxA, Wd2, bd2, x2,
                                              192);
  KNN64_PASS(x2, 192)
  dilate_kernel<<<NPTS / 4, 256, 0, stream>>>(x2, 192, idxA, Wd3, bd3, x3,
                                              192);
#undef KNN64_PASS

  // stage 3: MLP head
  gemm128_kernel<128><<<dim3(1024 / 128, NPTS / 128), 256, 0, stream>>>(
      xcat, 192, 192, Wl, 1024, bl, h1, 1024, 1);
  gemm128_kernel<64><<<dim3(256 / 64, NPTS / 128), 256, 0, stream>>>(
      h1, 1024, 1024, Wm1, 256, bm1, h2, 256, 1);
  gemm128_kernel<64><<<dim3(128 / 64, NPTS / 128), 256, 0, stream>>>(
      h2, 256, 256, Wm2, 128, bm2, h3, 128, 1);
  final_kernel<<<NPTS / 16, 256, 0, stream>>>(h3, Wm3, bm3, out);
}

// Round 11
// 1206.777 us; speedup vs baseline: 3.9424x; 1.1549x over previous
//
#include <hip/hip_runtime.h>
#include <math.h>

#define NPTS 8192
#define KNN 20
#define KSEL 8   // per-stream ripple depth; T~ stays a valid upper bound
#define CAP 256

// monotonic u32 key: a<b (float, incl. inf) <=> fkey(a)<fkey(b)
__device__ __forceinline__ uint32_t fkey(float v) {
  uint32_t b = __float_as_uint(v);
  return b ^ ((uint32_t)((int)b >> 31) | 0x80000000u);
}

// key-only sorted-insert, depth 8: 2 VALU/step (v_min_u32/v_max_u32)
__device__ __forceinline__ void insert8k(uint32_t (&d)[KSEL], uint32_t key) {
#pragma unroll
  for (int r = 0; r < KSEL; ++r) {
    uint32_t nd = min(d[r], key);
    key = max(d[r], key);
    d[r] = nd;
  }
}

// ---------------------------------------------------------------------------
// sq[i] = sum_d x[i][d]^2
// ---------------------------------------------------------------------------
__global__ void sqnorm_kernel(const float* __restrict__ x, int ldx, int D,
                              float* __restrict__ sq) {
  int i = blockIdx.x * blockDim.x + threadIdx.x;
  if (i >= NPTS) return;
  const float* xr = x + (size_t)i * ldx;
  float s = 0.f;
  for (int d = 0; d < D; ++d) { float v = xr[d]; s += v * v; }
  sq[i] = s;
}

// ---------------------------------------------------------------------------
// 64-D approx pass: fused fp32 GEMM + key-only top-8 per stream over the
// HALF subset (cands 0..4095). T~ = 20th of union(top-8 x 32 streams) >=
// exact 20th -> recovery stays exact. ROUND-11: T14 async-stage split --
// next phase's 4 global float4 loads issue BEFORE compute/selection, LDS
// commit after the barrier; ripple depth 20->8 (16 ops vs 40).
// Grid (64 qb, 16 chunks of 256), 256 thr, 48 KB LDS, (256,2).
// ---------------------------------------------------------------------------
#define WRITE_S(QR, BASE)                                                   \
  {                                                                         \
    const int cc = (4 * bg) & 31;                                           \
    const int jbase = cb + (QR)*32 + cc;                                    \
    _Pragma("unroll") for (int u = 0; u < 8; ++u) {                         \
      const int row = 4 * am + (u & 3) + 64 * (u >> 2);                     \
      const int gq = qb * 128 + row;                                        \
      const int sw = ((row & 7) ^ ((row >> 2) & 7)) << 2;                   \
      uint32_t k0 = fkey(fmaf(-2.f, acc[u][(BASE) + 0], sc[(BASE) + 0]));   \
      uint32_t k1 = fkey(fmaf(-2.f, acc[u][(BASE) + 1], sc[(BASE) + 1]));   \
      uint32_t k2 = fkey(fmaf(-2.f, acc[u][(BASE) + 2], sc[(BASE) + 2]));   \
      uint32_t k3 = fkey(fmaf(-2.f, acc[u][(BASE) + 3], sc[(BASE) + 3]));   \
      if (jbase + 0 == gq) k0 = 0xFFFFFFFFu;                                \
      if (jbase + 1 == gq) k1 = 0xFFFFFFFFu;                                \
      if (jbase + 2 == gq) k2 = 0xFFFFFFFFu;                                \
      if (jbase + 3 == gq) k3 = 0xFFFFFFFFu;                                \
      *(uint4*)&S[row * 32 + (cc ^ sw)] = make_uint4(k0, k1, k2, k3);       \
    }                                                                       \
  }

#define COMMIT_CS()                                                         \
  {                                                                         \
    Cs[(ck + 0) * 128 + cn] = p0.x;  Cs[(ck + 1) * 128 + cn] = p0.y;        \
    Cs[(ck + 2) * 128 + cn] = p0.z;  Cs[(ck + 3) * 128 + cn] = p0.w;        \
    Cs[(ck + 4) * 128 + cn] = p1.x;  Cs[(ck + 5) * 128 + cn] = p1.y;        \
    Cs[(ck + 6) * 128 + cn] = p1.z;  Cs[(ck + 7) * 128 + cn] = p1.w;        \
    Cs[(ck + 8) * 128 + cn] = p2.x;  Cs[(ck + 9) * 128 + cn] = p2.y;        \
    Cs[(ck + 10) * 128 + cn] = p2.z; Cs[(ck + 11) * 128 + cn] = p2.w;       \
    Cs[(ck + 12) * 128 + cn] = p3.x; Cs[(ck + 13) * 128 + cn] = p3.y;       \
    Cs[(ck + 14) * 128 + cn] = p3.z; Cs[(ck + 15) * 128 + cn] = p3.w;       \
  }

#define ISSUE_CS(BASEROW, KOFF)                                             \
  {                                                                         \
    const float* src_ = &x[(size_t)((BASEROW) + cn) * LDX + (KOFF) + ck];   \
    p0 = *(const float4*)&src_[0];                                          \
    p1 = *(const float4*)&src_[4];                                          \
    p2 = *(const float4*)&src_[8];                                          \
    p3 = *(const float4*)&src_[12];                                         \
  }

template <int LDX>
__global__ __launch_bounds__(256, 2) void knn_gemm_kernel(
    const float* __restrict__ x, const float* __restrict__ sq,
    uint32_t* __restrict__ pk) {
  __shared__ float Qs[64 * 128];      // [k][q]
  __shared__ uint32_t CsS[32 * 128];  // Cs floats during compute; S keys
  float* const Cs = (float*)CsS;
  uint32_t* const S = CsS;
  const int t = threadIdx.x;
  const int qb = blockIdx.x;  // 0..63
  const int ch = blockIdx.y;  // 0..15 (subset cands ch*256 .. +255)
  const int am = t & 15;
  const int bg = (t >> 4) & 15;
  const int cn = t & 127;        // staging column (candidate row)
  const int ck = (t >> 7) * 16;  // staging k-base

  {  // Q stage
    const int q = t & 127;
    const int k0 = (t >> 7) * 32;
    const float* src = &x[(size_t)(qb * 128 + q) * LDX + k0];
#pragma unroll
    for (int c = 0; c < 8; ++c) {
      float4 v = *(const float4*)&src[c * 4];
      Qs[(k0 + c * 4 + 0) * 128 + q] = v.x;
      Qs[(k0 + c * 4 + 1) * 128 + q] = v.y;
      Qs[(k0 + c * 4 + 2) * 128 + q] = v.z;
      Qs[(k0 + c * 4 + 3) * 128 + q] = v.w;
    }
  }

  const int selq = t & 127, part = t >> 7;
  uint32_t dreg[KSEL];
#pragma unroll
  for (int r = 0; r < KSEL; ++r) dreg[r] = 0xFFFFFFFFu;

  float4 p0, p1, p2, p3;
  ISSUE_CS(ch * 256, 0)  // tile0 kh0

#pragma unroll 1
  for (int tile = 0; tile < 2; ++tile) {
    const int cb = ch * 256 + tile * 128;
    float acc[8][8] = {};
#pragma unroll
    for (int kh = 0; kh < 2; ++kh) {
      __syncthreads();  // CsS free (prev compute / prev S reads done)
      COMMIT_CS()
      if (kh == 0) {
        ISSUE_CS(cb, 32)  // this tile, kh1 -- hides under kh0 compute
      } else if (tile == 0) {
        ISSUE_CS(cb + 128, 0)  // next tile kh0 -- hides under S phases
      }
      __syncthreads();
#pragma unroll 4
      for (int k2 = 0; k2 < 32; ++k2) {
        const int k = kh * 32 + k2;
        float4 A0 = *(const float4*)&Qs[k * 128 + 4 * am];
        float4 A1 = *(const float4*)&Qs[k * 128 + 4 * am + 64];
        float4 B0 = *(const float4*)&Cs[k2 * 128 + 4 * bg];
        float4 B1 = *(const float4*)&Cs[k2 * 128 + 4 * bg + 64];
        float a[8] = {A0.x, A0.y, A0.z, A0.w, A1.x, A1.y, A1.z, A1.w};
        float b[8] = {B0.x, B0.y, B0.z, B0.w, B1.x, B1.y, B1.z, B1.w};
#pragma unroll
        for (int u = 0; u < 8; ++u)
#pragma unroll
          for (int v = 0; v < 8; ++v) acc[u][v] = fmaf(a[u], b[v], acc[u][v]);
      }
    }
    float4 s0 = *(const float4*)&sq[cb + 4 * bg];
    float4 s1 = *(const float4*)&sq[cb + 4 * bg + 64];
    float sc[8] = {s0.x, s0.y, s0.z, s0.w, s1.x, s1.y, s1.z, s1.w};

    const int qlow = bg >> 3;
    for (int qr = 0; qr < 4; ++qr) {
      __syncthreads();
      if (qr == qlow) WRITE_S(qr, 0);
      if (qr == 2 + qlow) WRITE_S(qr, 4);
      __syncthreads();
      const int swr = ((selq & 7) ^ ((selq >> 2) & 7)) << 2;
#pragma unroll
      for (int g_ = 0; g_ < 4; ++g_) {
        const int cc = part * 16 + g_ * 4;
        uint4 sv = *(const uint4*)&S[selq * 32 + (cc ^ swr)];
        uint32_t kv[4] = {sv.x, sv.y, sv.z, sv.w};
#pragma unroll
        for (int e = 0; e < 4; ++e) {
          if (kv[e] < dreg[KSEL - 1]) insert8k(dreg, kv[e]);
        }
      }
    }
  }
  const int l = ch * 2 + part;  // 32 lists
  uint32_t* pkq = pk + ((size_t)l * NPTS + (qb * 128 + selq)) * KSEL;
#pragma unroll
  for (int r = 0; r < KSEL; ++r) pkq[r] = dreg[r];
}

// ---------------------------------------------------------------------------
// Tournament over 32 sorted 8-entry key-lists -> T[q] = 20th of the union
// (a valid upper bound on the exact 20th; see round-11 theory).
// ---------------------------------------------------------------------------
__global__ __launch_bounds__(256) void knn_mergeT_kernel(
    const uint32_t* __restrict__ pk, uint32_t* __restrict__ T) {
  __shared__ uint32_t sk[8][32][KSEL];
  const int t = threadIdx.x;
  const int ql = t >> 5;
  const int l = t & 31;
  const int q = blockIdx.x * 8 + ql;
  const uint32_t* pkq = pk + ((size_t)l * NPTS + q) * KSEL;
#pragma unroll
  for (int r = 0; r < KSEL; ++r) sk[ql][l][r] = pkq[r];
  __syncthreads();
  int ptr = 0;
  uint32_t k = 0;
#pragma unroll 1
  for (int s = 0; s < KNN; ++s) {
    k = (ptr < KSEL) ? sk[ql][l][ptr] : 0xFFFFFFFFu;
    int src = l;
#pragma unroll
    for (int off = 16; off >= 1; off >>= 1) {
      uint32_t ok = __shfl_xor(k, off, 32);
      int osrc = __shfl_xor(src, off, 32);
      bool take = (ok < k) || (ok == k && osrc < src);
      k = take ? ok : k;
      src = take ? osrc : src;
    }
    if (l == src) ptr++;
  }
  if (l == 0) T[q] = k;  // 20th pop
}

// ---------------------------------------------------------------------------
// 64-D recovery: GEMM clone over ALL candidates with T14 prefetch; compact
// key <= T~ into CAP-slot buffers. Self packs to fkey(inf) -> excluded.
// ---------------------------------------------------------------------------
template <int LDX>
__global__ __launch_bounds__(256, 2) void knn_recover_kernel(
    const float* __restrict__ x, const float* __restrict__ sq,
    const uint32_t* __restrict__ T, uint32_t* __restrict__ cnt,
    uint32_t* __restrict__ cd, int* __restrict__ cj) {
  __shared__ float Qs[64 * 128];
  __shared__ float Cs[32 * 128];
  const int t = threadIdx.x;
  const int qb = blockIdx.x;
  const int ch = blockIdx.y;  // 0..15, full range: cands ch*512 .. +511
  const int am = t & 15;
  const int bg = (t >> 4) & 15;
  const int cn = t & 127;
  const int ck = (t >> 7) * 16;

  {  // Q stage
    const int q = t & 127;
    const int k0 = (t >> 7) * 32;
    const float* src = &x[(size_t)(qb * 128 + q) * LDX + k0];
#pragma unroll
    for (int c = 0; c < 8; ++c) {
      float4 v = *(const float4*)&src[c * 4];
      Qs[(k0 + c * 4 + 0) * 128 + q] = v.x;
      Qs[(k0 + c * 4 + 1) * 128 + q] = v.y;
      Qs[(k0 + c * 4 + 2) * 128 + q] = v.z;
      Qs[(k0 + c * 4 + 3) * 128 + q] = v.w;
    }
  }
  uint32_t Tq[8];
#pragma unroll
  for (int u = 0; u < 8; ++u)
    Tq[u] = T[qb * 128 + 4 * am + (u & 3) + 64 * (u >> 2)];

  float4 p0, p1, p2, p3;
  ISSUE_CS(ch * 512, 0)  // tile0 kh0

#pragma unroll 1
  for (int tile = 0; tile < 4; ++tile) {
    const int cb = ch * 512 + tile * 128;
    float acc[8][8] = {};
#pragma unroll
    for (int kh = 0; kh < 2; ++kh) {
      __syncthreads();
      COMMIT_CS()
      if (kh == 0) {
        ISSUE_CS(cb, 32)  // hides under kh0 compute
      } else if (tile < 3) {
        ISSUE_CS(cb + 128, 0)  // hides under kh1 compute + epilogue
      }
      __syncthreads();
#pragma unroll 4
      for (int k2 = 0; k2 < 32; ++k2) {
        const int k = kh * 32 + k2;
        float4 A0 = *(const float4*)&Qs[k * 128 + 4 * am];
        float4 A1 = *(const float4*)&Qs[k * 128 + 4 * am + 64];
        float4 B0 = *(const float4*)&Cs[k2 * 128 + 4 * bg];
        float4 B1 = *(const float4*)&Cs[k2 * 128 + 4 * bg + 64];
        float a[8] = {A0.x, A0.y, A0.z, A0.w, A1.x, A1.y, A1.z, A1.w};
        float b[8] = {B0.x, B0.y, B0.z, B0.w, B1.x, B1.y, B1.z, B1.w};
#pragma unroll
        for (int u = 0; u < 8; ++u)
#pragma unroll
          for (int v = 0; v < 8; ++v) acc[u][v] = fmaf(a[u], b[v], acc[u][v]);
      }
    }
    float4 s0 = *(const float4*)&sq[cb + 4 * bg];
    float4 s1 = *(const float4*)&sq[cb + 4 * bg + 64];
    float sc[8] = {s0.x, s0.y, s0.z, s0.w, s1.x, s1.y, s1.z, s1.w};
#pragma unroll
    for (int u = 0; u < 8; ++u) {
      const int gq = qb * 128 + 4 * am + (u & 3) + 64 * (u >> 2);
#pragma unroll
      for (int v = 0; v < 8; ++v) {
        const int j = cb + 4 * bg + (v & 3) + 64 * (v >> 2);
        float val = fmaf(-2.f, acc[u][v], sc[v]);
        if (j == gq) val = INFINITY;
        uint32_t key = fkey(val);
        if (key <= Tq[u]) {
          uint32_t slot = atomicAdd(&cnt[gq], 1u);
          if (slot < (uint32_t)CAP) {
            cd[(size_t)gq * CAP + slot] = key;
            cj[(size_t)gq * CAP + slot] = j;
          }
        }
      }
    }
  }
}

// ---------------------------------------------------------------------------
// 3-D approx pass: key-only top-8 over HALF subset (cands 0..4095),
// 32 chunks of 128 in LDS. Grid (32, 32), 256 threads.
// ---------------------------------------------------------------------------
__global__ __launch_bounds__(256) void knn_d3k_kernel(
    const float* __restrict__ x, const float* __restrict__ sq,
    uint32_t* __restrict__ pk) {
  __shared__ float4 Ct[128];
  const int t = threadIdx.x;
  const int q = blockIdx.x * 256 + t;
  const int ch = blockIdx.y;  // 0..31
  const int cb = ch * 128;
  if (t < 128)
    Ct[t] = make_float4(x[(cb + t) * 3], x[(cb + t) * 3 + 1],
                        x[(cb + t) * 3 + 2], sq[cb + t]);
  const float xi0 = x[q * 3], xi1 = x[q * 3 + 1], xi2 = x[q * 3 + 2];
  uint32_t dreg[KSEL];
#pragma unroll
  for (int r = 0; r < KSEL; ++r) dreg[r] = 0xFFFFFFFFu;
  __syncthreads();
#pragma unroll 1
  for (int c = 0; c < 128; ++c) {
    float4 cv = Ct[c];
    int j = cb + c;
    float val = fmaf(-2.f, xi0 * cv.x + xi1 * cv.y + xi2 * cv.z, cv.w);
    uint32_t key = fkey(val);
    if (j != q && key < dreg[KSEL - 1]) insert8k(dreg, key);
  }
  uint32_t* pkq = pk + ((size_t)ch * NPTS + q) * KSEL;
#pragma unroll
  for (int r = 0; r < KSEL; ++r) pkq[r] = dreg[r];
}

// ---------------------------------------------------------------------------
// 3-D recovery: stream all 8192 candidates, compact key <= T~.
// ---------------------------------------------------------------------------
__global__ __launch_bounds__(256) void knn_d3_recover_kernel(
    const float* __restrict__ x, const float* __restrict__ sq,
    const uint32_t* __restrict__ T, uint32_t* __restrict__ cnt,
    uint32_t* __restrict__ cd, int* __restrict__ cj) {
  __shared__ float4 Ct[256];
  const int t = threadIdx.x;
  const int q = blockIdx.x * 256 + t;
  const int ch = blockIdx.y;
  const int cb = ch * 256;
  Ct[t] = make_float4(x[(cb + t) * 3], x[(cb + t) * 3 + 1],
                      x[(cb + t) * 3 + 2], sq[cb + t]);
  const float xi0 = x[q * 3], xi1 = x[q * 3 + 1], xi2 = x[q * 3 + 2];
  const uint32_t Tq = T[q];
  __syncthreads();
#pragma unroll 1
  for (int c = 0; c < 256; ++c) {
    float4 cv = Ct[c];
    int j = cb + c;
    float val = fmaf(-2.f, xi0 * cv.x + xi1 * cv.y + xi2 * cv.z, cv.w);
    uint32_t key = fkey(val);
    if (j != q && key <= Tq) {
      uint32_t slot = atomicAdd(&cnt[q], 1u);
      if (slot < (uint32_t)CAP) {
        cd[(size_t)q * CAP + slot] = key;
        cj[(size_t)q * CAP + slot] = j;
      }
    }
  }
}

// ---------------------------------------------------------------------------
// Final select: one wave per query over <=CAP survivors; exact (key,j) order.
// ---------------------------------------------------------------------------
#define CSWAP(ka, ja, kb, jb)                                   \
  {                                                             \
    bool sw = (kb < ka) || (kb == ka && jb < ja);               \
    uint32_t tk = sw ? kb : ka; int tj = sw ? jb : ja;          \
    kb = sw ? ka : kb; jb = sw ? ja : jb;                       \
    ka = tk; ja = tj;                                           \
  }

__global__ __launch_bounds__(256) void knn_final_kernel(
    const uint32_t* __restrict__ cnt, const uint32_t* __restrict__ cd,
    const int* __restrict__ cj, int* __restrict__ idx_out) {
  const int t = threadIdx.x;
  const int w = t >> 6;
  const int l = t & 63;
  const int q = blockIdx.x * 4 + w;
  const int n = (int)min(cnt[q], (uint32_t)CAP);
  uint32_t k0 = 0xFFFFFFFFu, k1 = 0xFFFFFFFFu, k2 = 0xFFFFFFFFu,
           k3 = 0xFFFFFFFFu;
  int j0 = 0x7fffffff, j1 = 0x7fffffff, j2 = 0x7fffffff, j3 = 0x7fffffff;
  if (l < n) { k0 = cd[(size_t)q * CAP + l]; j0 = cj[(size_t)q * CAP + l]; }
  if (l + 64 < n) { k1 = cd[(size_t)q * CAP + l + 64]; j1 = cj[(size_t)q * CAP + l + 64]; }
  if (l + 128 < n) { k2 = cd[(size_t)q * CAP + l + 128]; j2 = cj[(size_t)q * CAP + l + 128]; }
  if (l + 192 < n) { k3 = cd[(size_t)q * CAP + l + 192]; j3 = cj[(size_t)q * CAP + l + 192]; }
  CSWAP(k0, j0, k1, j1); CSWAP(k2, j2, k3, j3);
  CSWAP(k0, j0, k2, j2); CSWAP(k1, j1, k3, j3);
  CSWAP(k1, j1, k2, j2);
#pragma unroll 1
  for (int s = 0; s < KNN; ++s) {
    uint32_t mk = k0;
    int mj = j0;
#pragma unroll
    for (int off = 32; off >= 1; off >>= 1) {
      uint32_t ok = __shfl_xor(mk, off, 64);
      int oj = __shfl_xor(mj, off, 64);
      bool take = (ok < mk) || (ok == mk && oj < mj);
      mk = take ? ok : mk;
      mj = take ? oj : mj;
    }
    if (k0 == mk && j0 == mj) {  // unique: j distinct per query
      k0 = k1; j0 = j1; k1 = k2; j1 = j2; k2 = k3; j2 = j3;
      k3 = 0xFFFFFFFFu; j3 = 0x7fffffff;
    }
    if (l == 0) idx_out[(size_t)q * KNN + s] = mj;
  }
}

// ---------------------------------------------------------------------------
// edge conv (unchanged)
// ---------------------------------------------------------------------------
__global__ __launch_bounds__(256) void edgeconv_kernel(
    const float* __restrict__ x, const int* __restrict__ idx,
    const float* __restrict__ W1, const float* __restrict__ b1,
    float* __restrict__ out) {
  const int i = blockIdx.x * 4 + (threadIdx.x >> 6);
  const int c = threadIdx.x & 63;
  float w0 = W1[c], w1 = W1[64 + c], w2 = W1[128 + c];
  float w3 = W1[192 + c], w4 = W1[256 + c], w5 = W1[320 + c];
  float xi0 = x[3 * i], xi1 = x[3 * i + 1], xi2 = x[3 * i + 2];
  float base = b1[c] + xi0 * w0 + xi1 * w1 + xi2 * w2;
  float m = -INFINITY;
#pragma unroll
  for (int k = 0; k < KNN; ++k) {
    int j = idx[i * KNN + k];
    float d0 = x[3 * j] - xi0, d1 = x[3 * j + 1] - xi1, d2 = x[3 * j + 2] - xi2;
    float h = base + d0 * w3 + d1 * w4 + d2 * w5;
    m = fmaxf(m, fmaxf(h, 0.f));
  }
  out[(size_t)i * 64 + c] = m;
}

// ---------------------------------------------------------------------------
// dilate (unchanged)
// ---------------------------------------------------------------------------
__global__ __launch_bounds__(256) void dilate_kernel(
    const float* __restrict__ xin, int ldin, const int* __restrict__ idx,
    const float* __restrict__ W, const float* __restrict__ bias,
    float* __restrict__ out, int ldout) {
  const int g = threadIdx.x >> 6;
  const int i = blockIdx.x * 4 + g;
  const int c = threadIdx.x & 63;
  __shared__ float dil[4][64];
  float m = -INFINITY;
#pragma unroll
  for (int k = 0; k < KNN; ++k) {
    int j = idx[i * KNN + k];
    m = fmaxf(m, xin[(size_t)j * ldin + c]);
  }
  dil[g][c] = m;
  __syncthreads();
  float acc = bias[c];
#pragma unroll
  for (int d = 0; d < 64; ++d) acc = fmaf(dil[g][d], W[d * 64 + c], acc);
  out[(size_t)i * ldout + c] = fmaxf(acc, 0.f) - xin[(size_t)i * ldin + c];
}

// ---------------------------------------------------------------------------
// BM=128 x BN tile fp32 GEMM (unchanged)
// ---------------------------------------------------------------------------
template <int BN>
__global__ __launch_bounds__(256) void gemm128_kernel(
    const float* __restrict__ A, int K, int ldA, const float* __restrict__ W,
    int N, const float* __restrict__ bias, float* __restrict__ C, int ldC,
    int relu) {
  constexpr int VN = BN / 16;
  __shared__ float As[16 * 128];
  __shared__ float Bs[16 * BN];
  const int t = threadIdx.x;
  const int bn = blockIdx.x * BN;
  const int bm = blockIdx.y * 128;
  const int am = t & 15;
  const int bg = (t >> 4) & 15;
  float acc[8][VN] = {};

  for (int k0 = 0; k0 < K; k0 += 16) {
    __syncthreads();
    {
      const int m = t & 127;
      const int ka = (t >> 7) * 8;
      const float* src = &A[(size_t)(bm + m) * ldA + k0 + ka];
      float4 v0 = *(const float4*)&src[0];
      float4 v1 = *(const float4*)&src[4];
      As[(ka + 0) * 128 + m] = v0.x;
      As[(ka + 1) * 128 + m] = v0.y;
      As[(ka + 2) * 128 + m] = v0.z;
      As[(ka + 3) * 128 + m] = v0.w;
      As[(ka + 4) * 128 + m] = v1.x;
      As[(ka + 5) * 128 + m] = v1.y;
      As[(ka + 6) * 128 + m] = v1.z;
      As[(ka + 7) * 128 + m] = v1.w;
    }
    if constexpr (BN == 128) {
      const int kb = t >> 4;
      const int n8 = (t & 15) * 8;
      const float* src = &W[(size_t)(k0 + kb) * N + bn + n8];
      float4 v0 = *(const float4*)&src[0];
      float4 v1 = *(const float4*)&src[4];
      *(float4*)&Bs[kb * BN + n8] = v0;
      *(float4*)&Bs[kb * BN + n8 + 4] = v1;
    } else {
      const int kb = t >> 4;
      const int n4 = (t & 15) * 4;
      const float* src = &W[(size_t)(k0 + kb) * N + bn + n4];
      *(float4*)&Bs[kb * BN + n4] = *(const float4*)&src[0];
    }
    __syncthreads();
#pragma unroll
    for (int k = 0; k < 16; ++k) {
      float4 A0 = *(const float4*)&As[k * 128 + 4 * am];
      float4 A1 = *(const float4*)&As[k * 128 + 4 * am + 64];
      float a[8] = {A0.x, A0.y, A0.z, A0.w, A1.x, A1.y, A1.z, A1.w};
      float b[VN];
      float4 B0 = *(const float4*)&Bs[k * BN + 4 * bg];
      b[0] = B0.x; b[1] = B0.y; b[2] = B0.z; b[3] = B0.w;
      if constexpr (BN == 128) {
        float4 B1 = *(const float4*)&Bs[k * BN + 4 * bg + 64];
        b[4] = B1.x; b[5] = B1.y; b[6] = B1.z; b[7] = B1.w;
      }
#pragma unroll
      for (int u = 0; u < 8; ++u)
#pragma unroll
        for (int v = 0; v < VN; ++v) acc[u][v] = fmaf(a[u], b[v], acc[u][v]);
    }
  }
#pragma unroll
  for (int u = 0; u < 8; ++u) {
    const int m = bm + 4 * am + (u & 3) + 64 * (u >> 2);
#pragma unroll
    for (int vq = 0; vq < VN / 4; ++vq) {
      const int n = bn + 4 * bg + 64 * vq;
      float4 o;
      float* po = (float*)&o;
#pragma unroll
      for (int e = 0; e < 4; ++e) {
        float val = acc[u][vq * 4 + e] + bias[n + e];
        po[e] = relu ? fmaxf(val, 0.f) : val;
      }
      *(float4*)&C[(size_t)m * ldC + n] = o;
    }
  }
}

// ---------------------------------------------------------------------------
// logits + log_softmax (unchanged)
// ---------------------------------------------------------------------------
__global__ __launch_bounds__(256) void final_kernel(
    const float* __restrict__ h3, const float* __restrict__ Wm3,
    const float* __restrict__ bm3, float* __restrict__ out) {
  __shared__ float hs[16][132];
  const int tid = threadIdx.x;
  const int r = tid >> 4, c = tid & 15;
  const int row0 = blockIdx.x * 16;
#pragma unroll
  for (int l = tid; l < 2048; l += 256)
    hs[l >> 7][l & 127] = h3[(size_t)row0 * 128 + l];
  __syncthreads();
  float acc = bm3[c];
#pragma unroll
  for (int d = 0; d < 128; ++d) acc = fmaf(hs[r][d], Wm3[d * 16 + c], acc);
  float mx = acc;
#pragma unroll
  for (int o = 8; o >= 1; o >>= 1) mx = fmaxf(mx, __shfl_xor(mx, o, 16));
  float e = expf(acc - mx);
  float s = e;
#pragma unroll
  for (int o = 8; o >= 1; o >>= 1) s += __shfl_xor(s, o, 16);
  out[(size_t)(row0 + r) * 16 + c] = (acc - mx) - logf(s);
}

// ---------------------------------------------------------------------------
extern "C" void kernel_launch(void* const* d_in, const int* in_sizes, int n_in,
                              void* d_out, int out_size, void* d_ws,
                              size_t ws_size, hipStream_t stream) {
  const float* x = (const float*)d_in[0];
  const float* W1 = (const float*)d_in[1];
  const float* b1 = (const float*)d_in[2];
  const float* Wd1 = (const float*)d_in[3];
  const float* bd1 = (const float*)d_in[4];
  const float* Wd2 = (const float*)d_in[5];
  const float* bd2 = (const float*)d_in[6];
  const float* Wd3 = (const float*)d_in[7];
  const float* bd3 = (const float*)d_in[8];
  const float* Wl = (const float*)d_in[9];
  const float* bl = (const float*)d_in[10];
  const float* Wm1 = (const float*)d_in[11];
  const float* bm1 = (const float*)d_in[12];
  const float* Wm2 = (const float*)d_in[13];
  const float* bm2 = (const float*)d_in[14];
  const float* Wm3 = (const float*)d_in[15];
  const float* bm3 = (const float*)d_in[16];
  float* out = (float*)d_out;

  char* ws = (char*)d_ws;
  float* sq = (float*)(ws + 0);              // 32 KB
  int* idxA = (int*)(ws + 32768);            // 640 KB
  float* xfeat = (float*)(ws + 1343488);     // 2 MB   [8192 x 64]
  float* xcat = (float*)(ws + 3440640);      // 6 MB   [8192 x 192]
  float* h1 = (float*)(ws + 9732096);        // 32 MB  [8192 x 1024]
  float* h2 = (float*)(ws + 43286528);       // 8 MB   [8192 x 256]
  float* h3 = (float*)(ws + 51675136);       // 4 MB   [8192 x 128]
  float* x1 = xcat;
  float* x2 = xcat + 64;
  float* x3 = xcat + 128;
  // knn scratch in the h1/h2 region (free until the head GEMMs):
  uint32_t* pk = (uint32_t*)(ws + 9732096);            // 8.4 MB (32 x 8 keys)
  uint32_t* T = (uint32_t*)(ws + 30703616);            // 32 KB
  uint32_t* cnt = (uint32_t*)(ws + 30703616 + 32768);  // 32 KB
  uint32_t* cd = (uint32_t*)(ws + 30703616 + 65536);   // 8 MB (CAP=256)
  int* cj = (int*)(ws + 30703616 + 65536 + 8388608);   // 8 MB -> ends 47.5MB

  // stage 1: edge conv on xyz (approx-T + exact recover path)
  sqnorm_kernel<<<32, 256, 0, stream>>>(x, 3, 3, sq);
  hipMemsetAsync(cnt, 0, NPTS * 4, stream);
  knn_d3k_kernel<<<dim3(32, 32), 256, 0, stream>>>(x, sq, pk);
  knn_mergeT_kernel<<<NPTS / 8, 256, 0, stream>>>(pk, T);
  knn_d3_recover_kernel<<<dim3(32, 32), 256, 0, stream>>>(x, sq, T, cnt, cd,
                                                          cj);
  knn_final_kernel<<<NPTS / 4, 256, 0, stream>>>(cnt, cd, cj, idxA);
  edgeconv_kernel<<<NPTS / 4, 256, 0, stream>>>(x, idxA, W1, b1, xfeat);

  // stage 2: three dilate blocks; 64-D kNN = half-subset keys + T~ + recover
#define KNN64_PASS(XIN, LDX)                                                 \
  sqnorm_kernel<<<32, 256, 0, stream>>>(XIN, LDX, 64, sq);                   \
  hipMemsetAsync(cnt, 0, NPTS * 4, stream);                                  \
  knn_gemm_kernel<LDX><<<dim3(64, 16), 256, 0, stream>>>(XIN, sq, pk);       \
  knn_mergeT_kernel<<<NPTS / 8, 256, 0, stream>>>(pk, T);                    \
  knn_recover_kernel<LDX><<<dim3(64, 16), 256, 0, stream>>>(XIN, sq, T, cnt, \
                                                            cd, cj);         \
  knn_final_kernel<<<NPTS / 4, 256, 0, stream>>>(cnt, cd, cj, idxA);

  KNN64_PASS(xfeat, 64)
  dilate_kernel<<<NPTS / 4, 256, 0, stream>>>(xfeat, 64, idxA, Wd1, bd1, x1,
                                              192);
  KNN64_PASS(x1, 192)
  dilate_kernel<<<NPTS / 4, 256, 0, stream>>>(x1, 192, idxA, Wd2, bd2, x2,
                                              192);
  KNN64_PASS(x2, 192)
  dilate_kernel<<<NPTS / 4, 256, 0, stream>>>(x2, 192, idxA, Wd3, bd3, x3,
                                              192);
#undef KNN64_PASS

  // stage 3: MLP head
  gemm128_kernel<128><<<dim3(1024 / 128, NPTS / 128), 256, 0, stream>>>(
      xcat, 192, 192, Wl, 1024, bl, h1, 1024, 1);
  gemm128_kernel<64><<<dim3(256 / 64, NPTS / 128), 256, 0, stream>>>(
      h1, 1024, 1024, Wm1, 256, bm1, h2, 256, 1);
  gemm128_kernel<64><<<dim3(128 / 64, NPTS / 128), 256, 0, stream>>>(
      h2, 256, 256, Wm2, 128, bm2, h3, 128, 1);
  final_kernel<<<NPTS / 16, 256, 0, stream>>>(h3, Wm3, bm3, out);
}